// Round 10
// baseline (305.938 us; speedup 1.0000x reference)
//
#include <hip/hip_runtime.h>
#include <hip/hip_bf16.h>

#define N_NODES 50000
#define N_EDGES 800000
#define DIM 64
#define ODIM 32
#define N_GRAPHS 512
#define SCAN_NB ((N_NODES + 255) / 256)   // 196
#define NXCD 8
#define DST_RANGE ((N_NODES + NXCD - 1) / NXCD)   // 6250

// ---- graph prep: counting-sort edges by dst into CSR ----

__global__ void count_deg(const int* __restrict__ dst, int* __restrict__ cnt) {
    int base = blockIdx.x * 1024;
#pragma unroll
    for (int i = 0; i < 4; ++i) {
        int e = base + i * 256 + threadIdx.x;
        if (e < N_EDGES) atomicAdd(&cnt[__builtin_nontemporal_load(&dst[e])], 1);
    }
}

// ---- 2-phase exclusive scan over cnt[N_NODES] ----

__global__ __launch_bounds__(256) void scan_p1(const int* __restrict__ cnt,
                                               int* __restrict__ blocksum) {
    __shared__ int ws[4];
    int i = blockIdx.x * 256 + threadIdx.x;
    int v = (i < N_NODES) ? cnt[i] : 0;
    for (int d = 32; d > 0; d >>= 1) v += __shfl_down(v, d, 64);
    int lane = threadIdx.x & 63, wid = threadIdx.x >> 6;
    if (lane == 0) ws[wid] = v;
    __syncthreads();
    if (threadIdx.x == 0) blocksum[blockIdx.x] = ws[0] + ws[1] + ws[2] + ws[3];
}

__global__ __launch_bounds__(256) void scan_p3(const int* __restrict__ cnt,
                                               const int* __restrict__ blocksum,
                                               int* __restrict__ off,
                                               int* __restrict__ cursor,
                                               float* __restrict__ inv_sqrt,
                                               float* __restrict__ invdeg) {
    __shared__ int wtot[4];
    __shared__ int bb[SCAN_NB + 1];
    {
        int t = threadIdx.x;
        int v = (t < SCAN_NB) ? blocksum[t] : 0;
        int lane = t & 63, wid = t >> 6;
        int incl = v;
        for (int d = 1; d < 64; d <<= 1) {
            int u = __shfl_up(incl, d, 64);
            if (lane >= d) incl += u;
        }
        if (lane == 63) wtot[wid] = incl;
        __syncthreads();
        int base = 0;
        for (int w = 0; w < wid; ++w) base += wtot[w];
        incl += base;
        if (t <= SCAN_NB) bb[t] = incl - v;   // exclusive; bb[SCAN_NB] = total
        __syncthreads();
    }
    if (blockIdx.x == 0 && threadIdx.x == 0) off[N_NODES] = bb[SCAN_NB];
    __syncthreads();

    int i = blockIdx.x * 256 + threadIdx.x;
    int v = (i < N_NODES) ? cnt[i] : 0;
    int lane = threadIdx.x & 63, wid = threadIdx.x >> 6;
    int incl = v;
    for (int d = 1; d < 64; d <<= 1) {
        int u = __shfl_up(incl, d, 64);
        if (lane >= d) incl += u;
    }
    __syncthreads();
    if (lane == 63) wtot[wid] = incl;
    __syncthreads();
    int base = bb[blockIdx.x];
    for (int w = 0; w < wid; ++w) base += wtot[w];
    int excl = base + incl - v;
    if (i < N_NODES) {
        off[i] = excl; cursor[i] = excl;
        float d = (float)(v + 1);   // self-loop
        inv_sqrt[i] = rsqrtf(d);
        invdeg[i]   = 1.0f / d;
    }
}

// XCD-partitioned scatter: block = (chunk, range); blockIdx%8 -> XCD round-robin.
// 4 edges per thread for ILP on the atomic->store chain.
__global__ void scatter_edges(const int* __restrict__ src, const int* __restrict__ dst,
                              const float* __restrict__ inv_sqrt,
                              int* __restrict__ cursor,
                              int2* __restrict__ edges) {
    int chunk = blockIdx.x >> 3;
    int range = blockIdx.x & 7;
    int base  = chunk * 1024;
    int lo    = range * DST_RANGE;
    int d[4], s[4];
    bool ok[4];
#pragma unroll
    for (int i = 0; i < 4; ++i) {
        int e = base + i * 256 + threadIdx.x;
        ok[i] = (e < N_EDGES);
        d[i] = ok[i] ? dst[e] : 0;
        s[i] = ok[i] ? src[e] : 0;
        ok[i] = ok[i] && ((unsigned)(d[i] - lo) < (unsigned)DST_RANGE);
    }
#pragma unroll
    for (int i = 0; i < 4; ++i) {
        if (ok[i]) {
            int pos = atomicAdd(&cursor[d[i]], 1);
            float w = inv_sqrt[s[i]] * inv_sqrt[d[i]];
            edges[pos] = make_int2(s[i], __float_as_int(w));
        }
    }
}

// ---- h = X @ W  (N x 64 @ 64 x 64); fp32 Y + bf16 copy ----
// W in NATURAL [k][j] layout in LDS: lane j reads Ws[k*64+j] -> bank j%32,
// 2-way alias only (free). Staging writes coalesced, conflict-free.

__global__ __launch_bounds__(256) void gemm64(const float* __restrict__ X,
                                              const float* __restrict__ W,
                                              float* __restrict__ Y,
                                              __hip_bfloat16* __restrict__ Ybf,
                                              int nrows) {
    __shared__ float Ws[64 * 64];
    for (int i = threadIdx.x; i < 64 * 64; i += 256) Ws[i] = W[i];
    __syncthreads();
    int wave = threadIdx.x >> 6;
    int j    = threadIdx.x & 63;
    int row0 = (blockIdx.x * 4 + wave) * 8;
    if (row0 >= nrows) return;
    float acc[8] = {0,0,0,0,0,0,0,0};
    const float* x0 = X + (size_t)row0 * DIM;   // wave-uniform
    int nr = (row0 + 8 <= nrows) ? 8 : (nrows - row0);
    if (nr == 8) {
#pragma unroll
        for (int k4 = 0; k4 < 16; ++k4) {
            float w0 = Ws[(4 * k4 + 0) * 64 + j];
            float w1 = Ws[(4 * k4 + 1) * 64 + j];
            float w2 = Ws[(4 * k4 + 2) * 64 + j];
            float w3 = Ws[(4 * k4 + 3) * 64 + j];
#pragma unroll
            for (int r = 0; r < 8; ++r) {
                float4 x4 = *(const float4*)&x0[r * DIM + k4 * 4];
                acc[r] = fmaf(x4.x, w0, acc[r]);
                acc[r] = fmaf(x4.y, w1, acc[r]);
                acc[r] = fmaf(x4.z, w2, acc[r]);
                acc[r] = fmaf(x4.w, w3, acc[r]);
            }
        }
    } else {
        for (int k4 = 0; k4 < 16; ++k4) {
            float w0 = Ws[(4 * k4 + 0) * 64 + j];
            float w1 = Ws[(4 * k4 + 1) * 64 + j];
            float w2 = Ws[(4 * k4 + 2) * 64 + j];
            float w3 = Ws[(4 * k4 + 3) * 64 + j];
            for (int r = 0; r < nr; ++r) {
                float4 x4 = *(const float4*)&x0[r * DIM + k4 * 4];
                acc[r] = fmaf(x4.x, w0, acc[r]);
                acc[r] = fmaf(x4.y, w1, acc[r]);
                acc[r] = fmaf(x4.z, w2, acc[r]);
                acc[r] = fmaf(x4.w, w3, acc[r]);
            }
        }
    }
    for (int r = 0; r < nr; ++r) {
        Y[(size_t)(row0 + r) * DIM + j]   = acc[r];
        Ybf[(size_t)(row0 + r) * DIM + j] = __float2bfloat16(acc[r]);
    }
}

// ---- fused: layer-1 aggregate (+bias1, relu) THEN layer-2 gemm (@W2) ----
// W2 in natural layout (b32 reads, conflict-free); h row broadcast from LDS.

__global__ __launch_bounds__(256) void agg_gemm(const float* __restrict__ H,
                                                const __hip_bfloat16* __restrict__ Hbf,
                                                const int* __restrict__ off,
                                                const int2* __restrict__ edges,
                                                const float* __restrict__ invdeg,
                                                const float* __restrict__ bias,
                                                const float* __restrict__ W2,
                                                float* __restrict__ Y,
                                                __hip_bfloat16* __restrict__ Ybf2) {
    __shared__ float Ws[64 * 64];
    __shared__ float rowbuf[4][64];
    for (int i = threadIdx.x; i < 64 * 64; i += 256) Ws[i] = W2[i];
    __syncthreads();
    int wave = threadIdx.x >> 6;
    int j    = threadIdx.x & 63;
    int node = blockIdx.x * 4 + wave;
    if (node < N_NODES) {
        float acc = H[(size_t)node * DIM + j] * invdeg[node];
        int s0 = off[node], s1 = off[node + 1];
        int k = s0;
        for (; k + 7 < s1; k += 8) {
            int2 eA = edges[k],   eB = edges[k+1], eC = edges[k+2], eD = edges[k+3];
            int2 eE = edges[k+4], eF = edges[k+5], eG = edges[k+6], eH = edges[k+7];
            float hA = __bfloat162float(Hbf[(size_t)eA.x * DIM + j]);
            float hB = __bfloat162float(Hbf[(size_t)eB.x * DIM + j]);
            float hC = __bfloat162float(Hbf[(size_t)eC.x * DIM + j]);
            float hD = __bfloat162float(Hbf[(size_t)eD.x * DIM + j]);
            float hE = __bfloat162float(Hbf[(size_t)eE.x * DIM + j]);
            float hF = __bfloat162float(Hbf[(size_t)eF.x * DIM + j]);
            float hG = __bfloat162float(Hbf[(size_t)eG.x * DIM + j]);
            float hH = __bfloat162float(Hbf[(size_t)eH.x * DIM + j]);
            acc = fmaf(hA, __int_as_float(eA.y), acc);
            acc = fmaf(hB, __int_as_float(eB.y), acc);
            acc = fmaf(hC, __int_as_float(eC.y), acc);
            acc = fmaf(hD, __int_as_float(eD.y), acc);
            acc = fmaf(hE, __int_as_float(eE.y), acc);
            acc = fmaf(hF, __int_as_float(eF.y), acc);
            acc = fmaf(hG, __int_as_float(eG.y), acc);
            acc = fmaf(hH, __int_as_float(eH.y), acc);
        }
        for (; k < s1; ++k) {
            int2 eA = edges[k];
            acc = fmaf(__bfloat162float(Hbf[(size_t)eA.x * DIM + j]), __int_as_float(eA.y), acc);
        }
        rowbuf[wave][j] = fmaxf(acc + bias[j], 0.f);
    }
    __syncthreads();
    if (node < N_NODES) {
        const float* hr = rowbuf[wave];
        float acc2 = 0.f;
#pragma unroll
        for (int k4 = 0; k4 < 16; ++k4) {
            float4 h4 = *(const float4*)&hr[k4 * 4];   // same-addr broadcast: free
            acc2 = fmaf(h4.x, Ws[(4 * k4 + 0) * 64 + j], acc2);
            acc2 = fmaf(h4.y, Ws[(4 * k4 + 1) * 64 + j], acc2);
            acc2 = fmaf(h4.z, Ws[(4 * k4 + 2) * 64 + j], acc2);
            acc2 = fmaf(h4.w, Ws[(4 * k4 + 3) * 64 + j], acc2);
        }
        Y[(size_t)node * DIM + j]    = acc2;
        Ybf2[(size_t)node * DIM + j] = __float2bfloat16(acc2);
    }
}

// ---- layer-2 aggregate (+bias2, relu) ----

__global__ __launch_bounds__(256) void aggregate(const float* __restrict__ H,
                                                 const __hip_bfloat16* __restrict__ Hbf,
                                                 const int* __restrict__ off,
                                                 const int2* __restrict__ edges,
                                                 const float* __restrict__ invdeg,
                                                 const float* __restrict__ bias,
                                                 float* __restrict__ Y) {
    int node = blockIdx.x * 4 + (threadIdx.x >> 6);
    int j    = threadIdx.x & 63;
    if (node >= N_NODES) return;
    float acc = H[(size_t)node * DIM + j] * invdeg[node];
    int s0 = off[node], s1 = off[node + 1];
    int k = s0;
    for (; k + 7 < s1; k += 8) {
        int2 eA = edges[k],   eB = edges[k+1], eC = edges[k+2], eD = edges[k+3];
        int2 eE = edges[k+4], eF = edges[k+5], eG = edges[k+6], eH = edges[k+7];
        float hA = __bfloat162float(Hbf[(size_t)eA.x * DIM + j]);
        float hB = __bfloat162float(Hbf[(size_t)eB.x * DIM + j]);
        float hC = __bfloat162float(Hbf[(size_t)eC.x * DIM + j]);
        float hD = __bfloat162float(Hbf[(size_t)eD.x * DIM + j]);
        float hE = __bfloat162float(Hbf[(size_t)eE.x * DIM + j]);
        float hF = __bfloat162float(Hbf[(size_t)eF.x * DIM + j]);
        float hG = __bfloat162float(Hbf[(size_t)eG.x * DIM + j]);
        float hH = __bfloat162float(Hbf[(size_t)eH.x * DIM + j]);
        acc = fmaf(hA, __int_as_float(eA.y), acc);
        acc = fmaf(hB, __int_as_float(eB.y), acc);
        acc = fmaf(hC, __int_as_float(eC.y), acc);
        acc = fmaf(hD, __int_as_float(eD.y), acc);
        acc = fmaf(hE, __int_as_float(eE.y), acc);
        acc = fmaf(hF, __int_as_float(eF.y), acc);
        acc = fmaf(hG, __int_as_float(eG.y), acc);
        acc = fmaf(hH, __int_as_float(eH.y), acc);
    }
    for (; k < s1; ++k) {
        int2 eA = edges[k];
        acc = fmaf(__bfloat162float(Hbf[(size_t)eA.x * DIM + j]), __int_as_float(eA.y), acc);
    }
    acc += bias[j];
    Y[(size_t)node * DIM + j] = fmaxf(acc, 0.f);
}

// ---- fused mean-pool + FC: one block per graph, batch is sorted ----

__global__ __launch_bounds__(256) void pool_fc(const float* __restrict__ H,
                                               const int* __restrict__ batch,
                                               const float* __restrict__ fcW,
                                               const float* __restrict__ fcb,
                                               float* __restrict__ out) {
    __shared__ float part[4][64];
    __shared__ float mean[64];
    int g = blockIdx.x;
    int lo = 0, hi = N_NODES;
    while (lo < hi) { int mid = (lo + hi) >> 1; if (batch[mid] < g) lo = mid + 1; else hi = mid; }
    int start = lo;
    hi = N_NODES;
    while (lo < hi) { int mid = (lo + hi) >> 1; if (batch[mid] < g + 1) lo = mid + 1; else hi = mid; }
    int end = lo;

    int wave = threadIdx.x >> 6, j = threadIdx.x & 63;
    float acc = 0.f;
    for (int n = start + wave; n < end; n += 4)
        acc += H[(size_t)n * DIM + j];
    part[wave][j] = acc;
    __syncthreads();
    if (wave == 0) {
        float s = part[0][j] + part[1][j] + part[2][j] + part[3][j];
        mean[j] = s / fmaxf((float)(end - start), 1.0f);
    }
    __syncthreads();
    if (threadIdx.x < ODIM) {
        int jj = threadIdx.x;
        float a = fcb[jj];
#pragma unroll
        for (int k = 0; k < DIM; ++k) a = fmaf(mean[k], fcW[k * ODIM + jj], a);
        out[g * ODIM + jj] = a;
    }
}

extern "C" void kernel_launch(void* const* d_in, const int* in_sizes, int n_in,
                              void* d_out, int out_size, void* d_ws, size_t ws_size,
                              hipStream_t stream) {
    const float* x    = (const float*)d_in[0];
    const float* W1   = (const float*)d_in[1];
    const float* b1   = (const float*)d_in[2];
    const float* W2   = (const float*)d_in[3];
    const float* b2   = (const float*)d_in[4];
    const float* fcW  = (const float*)d_in[5];
    const float* fcb  = (const float*)d_in[6];
    const int*   eidx = (const int*)d_in[7];
    const int*   batch= (const int*)d_in[8];
    const int* esrc = eidx;
    const int* edst = eidx + N_EDGES;
    float* out = (float*)d_out;

    char* ws = (char*)d_ws;
    size_t o = 0;
    auto alloc = [&](size_t bytes) {
        void* p = ws + o;
        o += (bytes + 255) & ~(size_t)255;
        return p;
    };
    float* bufA     = (float*)alloc((size_t)N_NODES * DIM * 4);
    float* bufB     = (float*)alloc((size_t)N_NODES * DIM * 4);
    __hip_bfloat16* bf1 = (__hip_bfloat16*)alloc((size_t)N_NODES * DIM * 2);
    __hip_bfloat16* bf2 = (__hip_bfloat16*)alloc((size_t)N_NODES * DIM * 2);
    int*   cnt      = (int*)  alloc((size_t)N_NODES * 4);
    int*   off      = (int*)  alloc((size_t)(N_NODES + 1) * 4);
    int*   cursor   = (int*)  alloc((size_t)N_NODES * 4);
    float* inv_sqrt = (float*)alloc((size_t)N_NODES * 4);
    float* invdeg   = (float*)alloc((size_t)N_NODES * 4);
    int2*  edges    = (int2*) alloc((size_t)N_EDGES * 8);
    int*   blocksum = (int*)  alloc((size_t)SCAN_NB * 4);

    hipMemsetAsync(cnt, 0, (size_t)N_NODES * 4, stream);

    count_deg<<<(N_EDGES + 1023) / 1024, 256, 0, stream>>>(edst, cnt);
    scan_p1<<<SCAN_NB, 256, 0, stream>>>(cnt, blocksum);
    scan_p3<<<SCAN_NB, 256, 0, stream>>>(cnt, blocksum, off, cursor, inv_sqrt, invdeg);
    scatter_edges<<<((N_EDGES + 1023) / 1024) * NXCD, 256, 0, stream>>>(esrc, edst, inv_sqrt, cursor, edges);

    gemm64<<<(N_NODES + 31) / 32, 256, 0, stream>>>(x, W1, bufA, bf1, N_NODES);
    agg_gemm<<<(N_NODES + 3) / 4, 256, 0, stream>>>(bufA, bf1, off, edges, invdeg, b1, W2, bufB, bf2);
    aggregate<<<(N_NODES + 3) / 4, 256, 0, stream>>>(bufB, bf2, off, edges, invdeg, b2, bufA);

    pool_fc<<<N_GRAPHS, 256, 0, stream>>>(bufA, batch, fcW, fcb, out);
}

// Round 11
// 301.924 us; speedup vs baseline: 1.0133x; 1.0133x over previous
//
#include <hip/hip_runtime.h>
#include <hip/hip_bf16.h>

#define N_NODES 50000
#define N_EDGES 800000
#define DIM 64
#define ODIM 32
#define N_GRAPHS 512
#define SCAN_NB ((N_NODES + 255) / 256)   // 196
#define NXCD 8
#define DST_RANGE ((N_NODES + NXCD - 1) / NXCD)   // 6250

// ---- graph prep: counting-sort edges by dst into CSR ----

__global__ void count_deg(const int* __restrict__ dst, int* __restrict__ cnt) {
    int e = blockIdx.x * blockDim.x + threadIdx.x;
    if (e < N_EDGES) atomicAdd(&cnt[__builtin_nontemporal_load(&dst[e])], 1);
}

// ---- 2-phase exclusive scan over cnt[N_NODES] ----

__global__ __launch_bounds__(256) void scan_p1(const int* __restrict__ cnt,
                                               int* __restrict__ blocksum) {
    __shared__ int ws[4];
    int i = blockIdx.x * 256 + threadIdx.x;
    int v = (i < N_NODES) ? cnt[i] : 0;
    for (int d = 32; d > 0; d >>= 1) v += __shfl_down(v, d, 64);
    int lane = threadIdx.x & 63, wid = threadIdx.x >> 6;
    if (lane == 0) ws[wid] = v;
    __syncthreads();
    if (threadIdx.x == 0) blocksum[blockIdx.x] = ws[0] + ws[1] + ws[2] + ws[3];
}

__global__ __launch_bounds__(256) void scan_p3(const int* __restrict__ cnt,
                                               const int* __restrict__ blocksum,
                                               int* __restrict__ off,
                                               int* __restrict__ cursor,
                                               float* __restrict__ inv_sqrt,
                                               float* __restrict__ invdeg) {
    __shared__ int wtot[4];
    __shared__ int bb[SCAN_NB + 1];
    {
        int t = threadIdx.x;
        int v = (t < SCAN_NB) ? blocksum[t] : 0;
        int lane = t & 63, wid = t >> 6;
        int incl = v;
        for (int d = 1; d < 64; d <<= 1) {
            int u = __shfl_up(incl, d, 64);
            if (lane >= d) incl += u;
        }
        if (lane == 63) wtot[wid] = incl;
        __syncthreads();
        int base = 0;
        for (int w = 0; w < wid; ++w) base += wtot[w];
        incl += base;
        if (t <= SCAN_NB) bb[t] = incl - v;   // exclusive; bb[SCAN_NB] = total
        __syncthreads();
    }
    if (blockIdx.x == 0 && threadIdx.x == 0) off[N_NODES] = bb[SCAN_NB];
    __syncthreads();

    int i = blockIdx.x * 256 + threadIdx.x;
    int v = (i < N_NODES) ? cnt[i] : 0;
    int lane = threadIdx.x & 63, wid = threadIdx.x >> 6;
    int incl = v;
    for (int d = 1; d < 64; d <<= 1) {
        int u = __shfl_up(incl, d, 64);
        if (lane >= d) incl += u;
    }
    __syncthreads();
    if (lane == 63) wtot[wid] = incl;
    __syncthreads();
    int base = bb[blockIdx.x];
    for (int w = 0; w < wid; ++w) base += wtot[w];
    int excl = base + incl - v;
    if (i < N_NODES) {
        off[i] = excl; cursor[i] = excl;
        float d = (float)(v + 1);   // self-loop
        inv_sqrt[i] = rsqrtf(d);
        invdeg[i]   = 1.0f / d;
    }
}

// XCD-partitioned scatter: block = (chunk, range); blockIdx%8 -> XCD round-robin
__global__ void scatter_edges(const int* __restrict__ src, const int* __restrict__ dst,
                              const float* __restrict__ inv_sqrt,
                              int* __restrict__ cursor,
                              int2* __restrict__ edges) {
    int chunk = blockIdx.x >> 3;
    int range = blockIdx.x & 7;
    int e = chunk * 256 + threadIdx.x;
    if (e >= N_EDGES) return;
    int d = dst[e];
    int lo = range * DST_RANGE;
    if ((unsigned)(d - lo) < (unsigned)DST_RANGE) {
        int s = src[e];
        int pos = atomicAdd(&cursor[d], 1);
        float w = inv_sqrt[s] * inv_sqrt[d];
        edges[pos] = make_int2(s, __float_as_int(w));
    }
}

// ---- h = X @ W  (N x 64 @ 64 x 64); fp32 Y + bf16 copy ----
// W in NATURAL [k][j] layout in LDS: lane j reads Ws[k*64+j] -> bank j%32,
// 2-way alias only (free). Staging writes coalesced, conflict-free.

__global__ __launch_bounds__(256) void gemm64(const float* __restrict__ X,
                                              const float* __restrict__ W,
                                              float* __restrict__ Y,
                                              __hip_bfloat16* __restrict__ Ybf,
                                              int nrows) {
    __shared__ float Ws[64 * 64];
    for (int i = threadIdx.x; i < 64 * 64; i += 256) Ws[i] = W[i];
    __syncthreads();
    int wave = threadIdx.x >> 6;
    int j    = threadIdx.x & 63;
    int row0 = (blockIdx.x * 4 + wave) * 8;
    if (row0 >= nrows) return;
    float acc[8] = {0,0,0,0,0,0,0,0};
    const float* x0 = X + (size_t)row0 * DIM;   // wave-uniform
    int nr = (row0 + 8 <= nrows) ? 8 : (nrows - row0);
    if (nr == 8) {
#pragma unroll
        for (int k4 = 0; k4 < 16; ++k4) {
            float w0 = Ws[(4 * k4 + 0) * 64 + j];
            float w1 = Ws[(4 * k4 + 1) * 64 + j];
            float w2 = Ws[(4 * k4 + 2) * 64 + j];
            float w3 = Ws[(4 * k4 + 3) * 64 + j];
#pragma unroll
            for (int r = 0; r < 8; ++r) {
                float4 x4 = *(const float4*)&x0[r * DIM + k4 * 4];
                acc[r] = fmaf(x4.x, w0, acc[r]);
                acc[r] = fmaf(x4.y, w1, acc[r]);
                acc[r] = fmaf(x4.z, w2, acc[r]);
                acc[r] = fmaf(x4.w, w3, acc[r]);
            }
        }
    } else {
        for (int k4 = 0; k4 < 16; ++k4) {
            float w0 = Ws[(4 * k4 + 0) * 64 + j];
            float w1 = Ws[(4 * k4 + 1) * 64 + j];
            float w2 = Ws[(4 * k4 + 2) * 64 + j];
            float w3 = Ws[(4 * k4 + 3) * 64 + j];
            for (int r = 0; r < nr; ++r) {
                float4 x4 = *(const float4*)&x0[r * DIM + k4 * 4];
                acc[r] = fmaf(x4.x, w0, acc[r]);
                acc[r] = fmaf(x4.y, w1, acc[r]);
                acc[r] = fmaf(x4.z, w2, acc[r]);
                acc[r] = fmaf(x4.w, w3, acc[r]);
            }
        }
    }
    for (int r = 0; r < nr; ++r) {
        Y[(size_t)(row0 + r) * DIM + j]   = acc[r];
        Ybf[(size_t)(row0 + r) * DIM + j] = __float2bfloat16(acc[r]);
    }
}

// ---- fused: layer-1 aggregate (+bias1, relu) THEN layer-2 gemm (@W2) ----
// 16 nodes per block: each wave gathers 4 nodes into its own rowbuf slice
// (no cross-wave sync), then GEMM with Ws register-reuse across the 4 nodes.
// W2 staging amortized 16x vs one-node-per-wave.

__global__ __launch_bounds__(256) void agg_gemm(const float* __restrict__ H,
                                                const __hip_bfloat16* __restrict__ Hbf,
                                                const int* __restrict__ off,
                                                const int2* __restrict__ edges,
                                                const float* __restrict__ invdeg,
                                                const float* __restrict__ bias,
                                                const float* __restrict__ W2,
                                                float* __restrict__ Y,
                                                __hip_bfloat16* __restrict__ Ybf2) {
    __shared__ float Ws[64 * 64];
    __shared__ float rowbuf[4][4][64];   // [wave][r][j]
    for (int i = threadIdx.x; i < 64 * 64; i += 256) Ws[i] = W2[i];
    __syncthreads();
    int wave = threadIdx.x >> 6;
    int j    = threadIdx.x & 63;
    int node0 = blockIdx.x * 16 + wave * 4;
    float bj = bias[j];
#pragma unroll
    for (int r = 0; r < 4; ++r) {
        int node = node0 + r;
        if (node >= N_NODES) break;
        float acc = H[(size_t)node * DIM + j] * invdeg[node];
        int s0 = off[node], s1 = off[node + 1];
        int k = s0;
        for (; k + 7 < s1; k += 8) {
            int2 eA = edges[k],   eB = edges[k+1], eC = edges[k+2], eD = edges[k+3];
            int2 eE = edges[k+4], eF = edges[k+5], eG = edges[k+6], eH = edges[k+7];
            float hA = __bfloat162float(Hbf[(size_t)eA.x * DIM + j]);
            float hB = __bfloat162float(Hbf[(size_t)eB.x * DIM + j]);
            float hC = __bfloat162float(Hbf[(size_t)eC.x * DIM + j]);
            float hD = __bfloat162float(Hbf[(size_t)eD.x * DIM + j]);
            float hE = __bfloat162float(Hbf[(size_t)eE.x * DIM + j]);
            float hF = __bfloat162float(Hbf[(size_t)eF.x * DIM + j]);
            float hG = __bfloat162float(Hbf[(size_t)eG.x * DIM + j]);
            float hH = __bfloat162float(Hbf[(size_t)eH.x * DIM + j]);
            acc = fmaf(hA, __int_as_float(eA.y), acc);
            acc = fmaf(hB, __int_as_float(eB.y), acc);
            acc = fmaf(hC, __int_as_float(eC.y), acc);
            acc = fmaf(hD, __int_as_float(eD.y), acc);
            acc = fmaf(hE, __int_as_float(eE.y), acc);
            acc = fmaf(hF, __int_as_float(eF.y), acc);
            acc = fmaf(hG, __int_as_float(eG.y), acc);
            acc = fmaf(hH, __int_as_float(eH.y), acc);
        }
        for (; k < s1; ++k) {
            int2 eA = edges[k];
            acc = fmaf(__bfloat162float(Hbf[(size_t)eA.x * DIM + j]), __int_as_float(eA.y), acc);
        }
        rowbuf[wave][r][j] = fmaxf(acc + bj, 0.f);
    }
    // same-wave LDS write->read: compiler inserts lgkmcnt wait; no barrier needed
    int nr = N_NODES - node0;
    if (nr <= 0) return;
    if (nr > 4) nr = 4;
    float acc2[4] = {0.f, 0.f, 0.f, 0.f};
#pragma unroll
    for (int k4 = 0; k4 < 16; ++k4) {
        float w0 = Ws[(4 * k4 + 0) * 64 + j];
        float w1 = Ws[(4 * k4 + 1) * 64 + j];
        float w2 = Ws[(4 * k4 + 2) * 64 + j];
        float w3 = Ws[(4 * k4 + 3) * 64 + j];
#pragma unroll
        for (int r = 0; r < 4; ++r) {
            float4 h4 = *(const float4*)&rowbuf[wave][r][k4 * 4];  // broadcast: free
            acc2[r] = fmaf(h4.x, w0, acc2[r]);
            acc2[r] = fmaf(h4.y, w1, acc2[r]);
            acc2[r] = fmaf(h4.z, w2, acc2[r]);
            acc2[r] = fmaf(h4.w, w3, acc2[r]);
        }
    }
    for (int r = 0; r < nr; ++r) {
        int node = node0 + r;
        Y[(size_t)node * DIM + j]    = acc2[r];
        Ybf2[(size_t)node * DIM + j] = __float2bfloat16(acc2[r]);
    }
}

// ---- layer-2 aggregate (+bias2, relu) ----

__global__ __launch_bounds__(256) void aggregate(const float* __restrict__ H,
                                                 const __hip_bfloat16* __restrict__ Hbf,
                                                 const int* __restrict__ off,
                                                 const int2* __restrict__ edges,
                                                 const float* __restrict__ invdeg,
                                                 const float* __restrict__ bias,
                                                 float* __restrict__ Y) {
    int node = blockIdx.x * 4 + (threadIdx.x >> 6);
    int j    = threadIdx.x & 63;
    if (node >= N_NODES) return;
    float acc = H[(size_t)node * DIM + j] * invdeg[node];
    int s0 = off[node], s1 = off[node + 1];
    int k = s0;
    for (; k + 7 < s1; k += 8) {
        int2 eA = edges[k],   eB = edges[k+1], eC = edges[k+2], eD = edges[k+3];
        int2 eE = edges[k+4], eF = edges[k+5], eG = edges[k+6], eH = edges[k+7];
        float hA = __bfloat162float(Hbf[(size_t)eA.x * DIM + j]);
        float hB = __bfloat162float(Hbf[(size_t)eB.x * DIM + j]);
        float hC = __bfloat162float(Hbf[(size_t)eC.x * DIM + j]);
        float hD = __bfloat162float(Hbf[(size_t)eD.x * DIM + j]);
        float hE = __bfloat162float(Hbf[(size_t)eE.x * DIM + j]);
        float hF = __bfloat162float(Hbf[(size_t)eF.x * DIM + j]);
        float hG = __bfloat162float(Hbf[(size_t)eG.x * DIM + j]);
        float hH = __bfloat162float(Hbf[(size_t)eH.x * DIM + j]);
        acc = fmaf(hA, __int_as_float(eA.y), acc);
        acc = fmaf(hB, __int_as_float(eB.y), acc);
        acc = fmaf(hC, __int_as_float(eC.y), acc);
        acc = fmaf(hD, __int_as_float(eD.y), acc);
        acc = fmaf(hE, __int_as_float(eE.y), acc);
        acc = fmaf(hF, __int_as_float(eF.y), acc);
        acc = fmaf(hG, __int_as_float(eG.y), acc);
        acc = fmaf(hH, __int_as_float(eH.y), acc);
    }
    for (; k < s1; ++k) {
        int2 eA = edges[k];
        acc = fmaf(__bfloat162float(Hbf[(size_t)eA.x * DIM + j]), __int_as_float(eA.y), acc);
    }
    acc += bias[j];
    Y[(size_t)node * DIM + j] = fmaxf(acc, 0.f);
}

// ---- fused mean-pool + FC: one block per graph, batch is sorted ----

__global__ __launch_bounds__(256) void pool_fc(const float* __restrict__ H,
                                               const int* __restrict__ batch,
                                               const float* __restrict__ fcW,
                                               const float* __restrict__ fcb,
                                               float* __restrict__ out) {
    __shared__ float part[4][64];
    __shared__ float mean[64];
    int g = blockIdx.x;
    int lo = 0, hi = N_NODES;
    while (lo < hi) { int mid = (lo + hi) >> 1; if (batch[mid] < g) lo = mid + 1; else hi = mid; }
    int start = lo;
    hi = N_NODES;
    while (lo < hi) { int mid = (lo + hi) >> 1; if (batch[mid] < g + 1) lo = mid + 1; else hi = mid; }
    int end = lo;

    int wave = threadIdx.x >> 6, j = threadIdx.x & 63;
    float acc = 0.f;
    for (int n = start + wave; n < end; n += 4)
        acc += H[(size_t)n * DIM + j];
    part[wave][j] = acc;
    __syncthreads();
    if (wave == 0) {
        float s = part[0][j] + part[1][j] + part[2][j] + part[3][j];
        mean[j] = s / fmaxf((float)(end - start), 1.0f);
    }
    __syncthreads();
    if (threadIdx.x < ODIM) {
        int jj = threadIdx.x;
        float a = fcb[jj];
#pragma unroll
        for (int k = 0; k < DIM; ++k) a = fmaf(mean[k], fcW[k * ODIM + jj], a);
        out[g * ODIM + jj] = a;
    }
}

extern "C" void kernel_launch(void* const* d_in, const int* in_sizes, int n_in,
                              void* d_out, int out_size, void* d_ws, size_t ws_size,
                              hipStream_t stream) {
    const float* x    = (const float*)d_in[0];
    const float* W1   = (const float*)d_in[1];
    const float* b1   = (const float*)d_in[2];
    const float* W2   = (const float*)d_in[3];
    const float* b2   = (const float*)d_in[4];
    const float* fcW  = (const float*)d_in[5];
    const float* fcb  = (const float*)d_in[6];
    const int*   eidx = (const int*)d_in[7];
    const int*   batch= (const int*)d_in[8];
    const int* esrc = eidx;
    const int* edst = eidx + N_EDGES;
    float* out = (float*)d_out;

    char* ws = (char*)d_ws;
    size_t o = 0;
    auto alloc = [&](size_t bytes) {
        void* p = ws + o;
        o += (bytes + 255) & ~(size_t)255;
        return p;
    };
    float* bufA     = (float*)alloc((size_t)N_NODES * DIM * 4);
    float* bufB     = (float*)alloc((size_t)N_NODES * DIM * 4);
    __hip_bfloat16* bf1 = (__hip_bfloat16*)alloc((size_t)N_NODES * DIM * 2);
    __hip_bfloat16* bf2 = (__hip_bfloat16*)alloc((size_t)N_NODES * DIM * 2);
    int*   cnt      = (int*)  alloc((size_t)N_NODES * 4);
    int*   off      = (int*)  alloc((size_t)(N_NODES + 1) * 4);
    int*   cursor   = (int*)  alloc((size_t)N_NODES * 4);
    float* inv_sqrt = (float*)alloc((size_t)N_NODES * 4);
    float* invdeg   = (float*)alloc((size_t)N_NODES * 4);
    int2*  edges    = (int2*) alloc((size_t)N_EDGES * 8);
    int*   blocksum = (int*)  alloc((size_t)SCAN_NB * 4);

    hipMemsetAsync(cnt, 0, (size_t)N_NODES * 4, stream);

    count_deg<<<(N_EDGES + 255) / 256, 256, 0, stream>>>(edst, cnt);
    scan_p1<<<SCAN_NB, 256, 0, stream>>>(cnt, blocksum);
    scan_p3<<<SCAN_NB, 256, 0, stream>>>(cnt, blocksum, off, cursor, inv_sqrt, invdeg);
    scatter_edges<<<((N_EDGES + 255) / 256) * NXCD, 256, 0, stream>>>(esrc, edst, inv_sqrt, cursor, edges);

    gemm64<<<(N_NODES + 31) / 32, 256, 0, stream>>>(x, W1, bufA, bf1, N_NODES);
    agg_gemm<<<(N_NODES + 15) / 16, 256, 0, stream>>>(bufA, bf1, off, edges, invdeg, b1, W2, bufB, bf2);
    aggregate<<<(N_NODES + 3) / 4, 256, 0, stream>>>(bufB, bf2, off, edges, invdeg, b2, bufA);

    pool_fc<<<N_GRAPHS, 256, 0, stream>>>(bufA, batch, fcW, fcb, out);
}

// Round 12
// 299.771 us; speedup vs baseline: 1.0206x; 1.0072x over previous
//
#include <hip/hip_runtime.h>
#include <hip/hip_bf16.h>

#define N_NODES 50000
#define N_EDGES 800000
#define DIM 64
#define ODIM 32
#define N_GRAPHS 512
#define SCAN_NB ((N_NODES + 255) / 256)   // 196
#define NXCD 8
#define DST_RANGE ((N_NODES + NXCD - 1) / NXCD)   // 6250

// ---- graph prep: counting-sort edges by dst into CSR ----

__global__ void count_deg(const int* __restrict__ dst, int* __restrict__ cnt) {
    int e = blockIdx.x * blockDim.x + threadIdx.x;
    if (e < N_EDGES) atomicAdd(&cnt[__builtin_nontemporal_load(&dst[e])], 1);
}

// ---- 2-phase exclusive scan over cnt[N_NODES] ----

__global__ __launch_bounds__(256) void scan_p1(const int* __restrict__ cnt,
                                               int* __restrict__ blocksum) {
    __shared__ int ws[4];
    int i = blockIdx.x * 256 + threadIdx.x;
    int v = (i < N_NODES) ? cnt[i] : 0;
    for (int d = 32; d > 0; d >>= 1) v += __shfl_down(v, d, 64);
    int lane = threadIdx.x & 63, wid = threadIdx.x >> 6;
    if (lane == 0) ws[wid] = v;
    __syncthreads();
    if (threadIdx.x == 0) blocksum[blockIdx.x] = ws[0] + ws[1] + ws[2] + ws[3];
}

__global__ __launch_bounds__(256) void scan_p3(const int* __restrict__ cnt,
                                               const int* __restrict__ blocksum,
                                               int* __restrict__ off,
                                               int* __restrict__ cursor,
                                               float* __restrict__ inv_sqrt,
                                               float* __restrict__ invdeg) {
    __shared__ int wtot[4];
    __shared__ int bb[SCAN_NB + 1];
    {
        int t = threadIdx.x;
        int v = (t < SCAN_NB) ? blocksum[t] : 0;
        int lane = t & 63, wid = t >> 6;
        int incl = v;
        for (int d = 1; d < 64; d <<= 1) {
            int u = __shfl_up(incl, d, 64);
            if (lane >= d) incl += u;
        }
        if (lane == 63) wtot[wid] = incl;
        __syncthreads();
        int base = 0;
        for (int w = 0; w < wid; ++w) base += wtot[w];
        incl += base;
        if (t <= SCAN_NB) bb[t] = incl - v;   // exclusive; bb[SCAN_NB] = total
        __syncthreads();
    }
    if (blockIdx.x == 0 && threadIdx.x == 0) off[N_NODES] = bb[SCAN_NB];
    __syncthreads();

    int i = blockIdx.x * 256 + threadIdx.x;
    int v = (i < N_NODES) ? cnt[i] : 0;
    int lane = threadIdx.x & 63, wid = threadIdx.x >> 6;
    int incl = v;
    for (int d = 1; d < 64; d <<= 1) {
        int u = __shfl_up(incl, d, 64);
        if (lane >= d) incl += u;
    }
    __syncthreads();
    if (lane == 63) wtot[wid] = incl;
    __syncthreads();
    int base = bb[blockIdx.x];
    for (int w = 0; w < wid; ++w) base += wtot[w];
    int excl = base + incl - v;
    if (i < N_NODES) {
        off[i] = excl; cursor[i] = excl;
        float d = (float)(v + 1);   // self-loop
        inv_sqrt[i] = rsqrtf(d);
        invdeg[i]   = 1.0f / d;
    }
}

// XCD-partitioned scatter: block = (chunk, range); blockIdx%8 -> XCD round-robin
__global__ void scatter_edges(const int* __restrict__ src, const int* __restrict__ dst,
                              const float* __restrict__ inv_sqrt,
                              int* __restrict__ cursor,
                              int2* __restrict__ edges) {
    int chunk = blockIdx.x >> 3;
    int range = blockIdx.x & 7;
    int e = chunk * 256 + threadIdx.x;
    if (e >= N_EDGES) return;
    int d = dst[e];
    int lo = range * DST_RANGE;
    if ((unsigned)(d - lo) < (unsigned)DST_RANGE) {
        int s = src[e];
        int pos = atomicAdd(&cursor[d], 1);
        float w = inv_sqrt[s] * inv_sqrt[d];
        edges[pos] = make_int2(s, __float_as_int(w));
    }
}

// gather-consume of one 8-edge batch (edge records already in registers)
#define CONSUME8(c0,c1,c2,c3,c4,c5,c6,c7)                                  \
    {                                                                      \
        float hA = __bfloat162float(Hbf[(size_t)c0.x * DIM + j]);          \
        float hB = __bfloat162float(Hbf[(size_t)c1.x * DIM + j]);          \
        float hC = __bfloat162float(Hbf[(size_t)c2.x * DIM + j]);          \
        float hD = __bfloat162float(Hbf[(size_t)c3.x * DIM + j]);          \
        float hE = __bfloat162float(Hbf[(size_t)c4.x * DIM + j]);          \
        float hF = __bfloat162float(Hbf[(size_t)c5.x * DIM + j]);          \
        float hG = __bfloat162float(Hbf[(size_t)c6.x * DIM + j]);          \
        float hH = __bfloat162float(Hbf[(size_t)c7.x * DIM + j]);          \
        acc = fmaf(hA, __int_as_float(c0.y), acc);                         \
        acc = fmaf(hB, __int_as_float(c1.y), acc);                         \
        acc = fmaf(hC, __int_as_float(c2.y), acc);                         \
        acc = fmaf(hD, __int_as_float(c3.y), acc);                         \
        acc = fmaf(hE, __int_as_float(c4.y), acc);                         \
        acc = fmaf(hF, __int_as_float(c5.y), acc);                         \
        acc = fmaf(hG, __int_as_float(c6.y), acc);                         \
        acc = fmaf(hH, __int_as_float(c7.y), acc);                         \
    }

// software-pipelined gather over [s0,s1): edge batch b+1 prefetched while
// batch b's row-gathers are in flight
#define GATHER_PIPELINED(s0, s1)                                           \
    {                                                                      \
        int k = (s0);                                                      \
        int nb = ((s1) - (s0)) >> 3;                                       \
        if (nb > 0) {                                                      \
            int2 c0 = edges[k+0], c1 = edges[k+1], c2 = edges[k+2],        \
                 c3 = edges[k+3], c4 = edges[k+4], c5 = edges[k+5],        \
                 c6 = edges[k+6], c7 = edges[k+7];                         \
            for (int b = 1; b < nb; ++b) {                                 \
                int kn = k + 8;                                            \
                int2 n0 = edges[kn+0], n1 = edges[kn+1], n2 = edges[kn+2], \
                     n3 = edges[kn+3], n4 = edges[kn+4], n5 = edges[kn+5], \
                     n6 = edges[kn+6], n7 = edges[kn+7];                   \
                CONSUME8(c0,c1,c2,c3,c4,c5,c6,c7);                         \
                c0=n0; c1=n1; c2=n2; c3=n3; c4=n4; c5=n5; c6=n6; c7=n7;    \
                k = kn;                                                    \
            }                                                              \
            CONSUME8(c0,c1,c2,c3,c4,c5,c6,c7);                             \
            k += 8;                                                        \
        }                                                                  \
        for (; k < (s1); ++k) {                                            \
            int2 eA = edges[k];                                            \
            acc = fmaf(__bfloat162float(Hbf[(size_t)eA.x * DIM + j]),      \
                       __int_as_float(eA.y), acc);                         \
        }                                                                  \
    }

// ---- h = X @ W  (N x 64 @ 64 x 64); fp32 Y + bf16 copy ----
// W in NATURAL [k][j] layout in LDS (2-way alias only: free).

__global__ __launch_bounds__(256) void gemm64(const float* __restrict__ X,
                                              const float* __restrict__ W,
                                              float* __restrict__ Y,
                                              __hip_bfloat16* __restrict__ Ybf,
                                              int nrows) {
    __shared__ float Ws[64 * 64];
    for (int i = threadIdx.x; i < 64 * 64; i += 256) Ws[i] = W[i];
    __syncthreads();
    int wave = threadIdx.x >> 6;
    int j    = threadIdx.x & 63;
    int row0 = (blockIdx.x * 4 + wave) * 8;
    if (row0 >= nrows) return;
    float acc[8] = {0,0,0,0,0,0,0,0};
    const float* x0 = X + (size_t)row0 * DIM;   // wave-uniform
    int nr = (row0 + 8 <= nrows) ? 8 : (nrows - row0);
    if (nr == 8) {
#pragma unroll
        for (int k4 = 0; k4 < 16; ++k4) {
            float w0 = Ws[(4 * k4 + 0) * 64 + j];
            float w1 = Ws[(4 * k4 + 1) * 64 + j];
            float w2 = Ws[(4 * k4 + 2) * 64 + j];
            float w3 = Ws[(4 * k4 + 3) * 64 + j];
#pragma unroll
            for (int r = 0; r < 8; ++r) {
                float4 x4 = *(const float4*)&x0[r * DIM + k4 * 4];
                acc[r] = fmaf(x4.x, w0, acc[r]);
                acc[r] = fmaf(x4.y, w1, acc[r]);
                acc[r] = fmaf(x4.z, w2, acc[r]);
                acc[r] = fmaf(x4.w, w3, acc[r]);
            }
        }
    } else {
        for (int k4 = 0; k4 < 16; ++k4) {
            float w0 = Ws[(4 * k4 + 0) * 64 + j];
            float w1 = Ws[(4 * k4 + 1) * 64 + j];
            float w2 = Ws[(4 * k4 + 2) * 64 + j];
            float w3 = Ws[(4 * k4 + 3) * 64 + j];
            for (int r = 0; r < nr; ++r) {
                float4 x4 = *(const float4*)&x0[r * DIM + k4 * 4];
                acc[r] = fmaf(x4.x, w0, acc[r]);
                acc[r] = fmaf(x4.y, w1, acc[r]);
                acc[r] = fmaf(x4.z, w2, acc[r]);
                acc[r] = fmaf(x4.w, w3, acc[r]);
            }
        }
    }
    for (int r = 0; r < nr; ++r) {
        Y[(size_t)(row0 + r) * DIM + j]   = acc[r];
        Ybf[(size_t)(row0 + r) * DIM + j] = __float2bfloat16(acc[r]);
    }
}

// ---- fused: layer-1 aggregate (+bias1, relu) THEN layer-2 gemm (@W2) ----
// 16 nodes/block (4 per wave), pipelined edge prefetch, W2 natural layout.

__global__ __launch_bounds__(256) void agg_gemm(const float* __restrict__ H,
                                                const __hip_bfloat16* __restrict__ Hbf,
                                                const int* __restrict__ off,
                                                const int2* __restrict__ edges,
                                                const float* __restrict__ invdeg,
                                                const float* __restrict__ bias,
                                                const float* __restrict__ W2,
                                                float* __restrict__ Y,
                                                __hip_bfloat16* __restrict__ Ybf2) {
    __shared__ float Ws[64 * 64];
    __shared__ float rowbuf[4][4][64];   // [wave][r][j]
    for (int i = threadIdx.x; i < 64 * 64; i += 256) Ws[i] = W2[i];
    __syncthreads();
    int wave = threadIdx.x >> 6;
    int j    = threadIdx.x & 63;
    int node0 = blockIdx.x * 16 + wave * 4;
    float bj = bias[j];
#pragma unroll
    for (int r = 0; r < 4; ++r) {
        int node = node0 + r;
        if (node >= N_NODES) break;
        float acc = H[(size_t)node * DIM + j] * invdeg[node];
        int s0 = off[node], s1 = off[node + 1];
        GATHER_PIPELINED(s0, s1);
        rowbuf[wave][r][j] = fmaxf(acc + bj, 0.f);
    }
    // same-wave LDS write->read: compiler inserts lgkmcnt wait; no barrier needed
    int nr = N_NODES - node0;
    if (nr <= 0) return;
    if (nr > 4) nr = 4;
    float acc2[4] = {0.f, 0.f, 0.f, 0.f};
#pragma unroll
    for (int k4 = 0; k4 < 16; ++k4) {
        float w0 = Ws[(4 * k4 + 0) * 64 + j];
        float w1 = Ws[(4 * k4 + 1) * 64 + j];
        float w2 = Ws[(4 * k4 + 2) * 64 + j];
        float w3 = Ws[(4 * k4 + 3) * 64 + j];
#pragma unroll
        for (int r = 0; r < 4; ++r) {
            float4 h4 = *(const float4*)&rowbuf[wave][r][k4 * 4];  // broadcast: free
            acc2[r] = fmaf(h4.x, w0, acc2[r]);
            acc2[r] = fmaf(h4.y, w1, acc2[r]);
            acc2[r] = fmaf(h4.z, w2, acc2[r]);
            acc2[r] = fmaf(h4.w, w3, acc2[r]);
        }
    }
    for (int r = 0; r < nr; ++r) {
        int node = node0 + r;
        Y[(size_t)node * DIM + j]    = acc2[r];
        Ybf2[(size_t)node * DIM + j] = __float2bfloat16(acc2[r]);
    }
}

// ---- layer-2 aggregate (+bias2, relu), pipelined edge prefetch ----

__global__ __launch_bounds__(256) void aggregate(const float* __restrict__ H,
                                                 const __hip_bfloat16* __restrict__ Hbf,
                                                 const int* __restrict__ off,
                                                 const int2* __restrict__ edges,
                                                 const float* __restrict__ invdeg,
                                                 const float* __restrict__ bias,
                                                 float* __restrict__ Y) {
    int node = blockIdx.x * 4 + (threadIdx.x >> 6);
    int j    = threadIdx.x & 63;
    if (node >= N_NODES) return;
    float acc = H[(size_t)node * DIM + j] * invdeg[node];
    int s0 = off[node], s1 = off[node + 1];
    GATHER_PIPELINED(s0, s1);
    acc += bias[j];
    Y[(size_t)node * DIM + j] = fmaxf(acc, 0.f);
}

// ---- fused mean-pool + FC: one block per graph, batch is sorted ----

__global__ __launch_bounds__(256) void pool_fc(const float* __restrict__ H,
                                               const int* __restrict__ batch,
                                               const float* __restrict__ fcW,
                                               const float* __restrict__ fcb,
                                               float* __restrict__ out) {
    __shared__ float part[4][64];
    __shared__ float mean[64];
    int g = blockIdx.x;
    int lo = 0, hi = N_NODES;
    while (lo < hi) { int mid = (lo + hi) >> 1; if (batch[mid] < g) lo = mid + 1; else hi = mid; }
    int start = lo;
    hi = N_NODES;
    while (lo < hi) { int mid = (lo + hi) >> 1; if (batch[mid] < g + 1) lo = mid + 1; else hi = mid; }
    int end = lo;

    int wave = threadIdx.x >> 6, j = threadIdx.x & 63;
    float acc = 0.f;
    for (int n = start + wave; n < end; n += 4)
        acc += H[(size_t)n * DIM + j];
    part[wave][j] = acc;
    __syncthreads();
    if (wave == 0) {
        float s = part[0][j] + part[1][j] + part[2][j] + part[3][j];
        mean[j] = s / fmaxf((float)(end - start), 1.0f);
    }
    __syncthreads();
    if (threadIdx.x < ODIM) {
        int jj = threadIdx.x;
        float a = fcb[jj];
#pragma unroll
        for (int k = 0; k < DIM; ++k) a = fmaf(mean[k], fcW[k * ODIM + jj], a);
        out[g * ODIM + jj] = a;
    }
}

extern "C" void kernel_launch(void* const* d_in, const int* in_sizes, int n_in,
                              void* d_out, int out_size, void* d_ws, size_t ws_size,
                              hipStream_t stream) {
    const float* x    = (const float*)d_in[0];
    const float* W1   = (const float*)d_in[1];
    const float* b1   = (const float*)d_in[2];
    const float* W2   = (const float*)d_in[3];
    const float* b2   = (const float*)d_in[4];
    const float* fcW  = (const float*)d_in[5];
    const float* fcb  = (const float*)d_in[6];
    const int*   eidx = (const int*)d_in[7];
    const int*   batch= (const int*)d_in[8];
    const int* esrc = eidx;
    const int* edst = eidx + N_EDGES;
    float* out = (float*)d_out;

    char* ws = (char*)d_ws;
    size_t o = 0;
    auto alloc = [&](size_t bytes) {
        void* p = ws + o;
        o += (bytes + 255) & ~(size_t)255;
        return p;
    };
    float* bufA     = (float*)alloc((size_t)N_NODES * DIM * 4);
    float* bufB     = (float*)alloc((size_t)N_NODES * DIM * 4);
    __hip_bfloat16* bf1 = (__hip_bfloat16*)alloc((size_t)N_NODES * DIM * 2);
    __hip_bfloat16* bf2 = (__hip_bfloat16*)alloc((size_t)N_NODES * DIM * 2);
    int*   cnt      = (int*)  alloc((size_t)N_NODES * 4);
    int*   off      = (int*)  alloc((size_t)(N_NODES + 1) * 4);
    int*   cursor   = (int*)  alloc((size_t)N_NODES * 4);
    float* inv_sqrt = (float*)alloc((size_t)N_NODES * 4);
    float* invdeg   = (float*)alloc((size_t)N_NODES * 4);
    int2*  edges    = (int2*) alloc((size_t)N_EDGES * 8);
    int*   blocksum = (int*)  alloc((size_t)SCAN_NB * 4);

    hipMemsetAsync(cnt, 0, (size_t)N_NODES * 4, stream);

    count_deg<<<(N_EDGES + 255) / 256, 256, 0, stream>>>(edst, cnt);
    scan_p1<<<SCAN_NB, 256, 0, stream>>>(cnt, blocksum);
    scan_p3<<<SCAN_NB, 256, 0, stream>>>(cnt, blocksum, off, cursor, inv_sqrt, invdeg);
    scatter_edges<<<((N_EDGES + 255) / 256) * NXCD, 256, 0, stream>>>(esrc, edst, inv_sqrt, cursor, edges);

    gemm64<<<(N_NODES + 31) / 32, 256, 0, stream>>>(x, W1, bufA, bf1, N_NODES);
    agg_gemm<<<(N_NODES + 15) / 16, 256, 0, stream>>>(bufA, bf1, off, edges, invdeg, b1, W2, bufB, bf2);
    aggregate<<<(N_NODES + 3) / 4, 256, 0, stream>>>(bufB, bf2, off, edges, invdeg, b2, bufA);

    pool_fc<<<N_GRAPHS, 256, 0, stream>>>(bufA, batch, fcW, fcb, out);
}

// Round 13
// 299.552 us; speedup vs baseline: 1.0213x; 1.0007x over previous
//
#include <hip/hip_runtime.h>
#include <hip/hip_bf16.h>

#define N_NODES 50000
#define N_EDGES 800000
#define DIM 64
#define ODIM 32
#define N_GRAPHS 512
#define SCAN_NB ((N_NODES + 255) / 256)   // 196
#define NXCD 8
#define DST_RANGE ((N_NODES + NXCD - 1) / NXCD)   // 6250

// ---- graph prep: counting-sort edges by dst into CSR ----

__global__ void count_deg(const int* __restrict__ dst, int* __restrict__ cnt) {
    int e = blockIdx.x * blockDim.x + threadIdx.x;
    if (e < N_EDGES) atomicAdd(&cnt[__builtin_nontemporal_load(&dst[e])], 1);
}

// ---- 2-phase exclusive scan over cnt[N_NODES] ----

__global__ __launch_bounds__(256) void scan_p1(const int* __restrict__ cnt,
                                               int* __restrict__ blocksum) {
    __shared__ int ws[4];
    int i = blockIdx.x * 256 + threadIdx.x;
    int v = (i < N_NODES) ? cnt[i] : 0;
    for (int d = 32; d > 0; d >>= 1) v += __shfl_down(v, d, 64);
    int lane = threadIdx.x & 63, wid = threadIdx.x >> 6;
    if (lane == 0) ws[wid] = v;
    __syncthreads();
    if (threadIdx.x == 0) blocksum[blockIdx.x] = ws[0] + ws[1] + ws[2] + ws[3];
}

__global__ __launch_bounds__(256) void scan_p3(const int* __restrict__ cnt,
                                               const int* __restrict__ blocksum,
                                               int* __restrict__ off,
                                               int* __restrict__ cursor,
                                               float* __restrict__ inv_sqrt,
                                               float* __restrict__ invdeg) {
    __shared__ int wtot[4];
    __shared__ int bb[SCAN_NB + 1];
    {
        int t = threadIdx.x;
        int v = (t < SCAN_NB) ? blocksum[t] : 0;
        int lane = t & 63, wid = t >> 6;
        int incl = v;
        for (int d = 1; d < 64; d <<= 1) {
            int u = __shfl_up(incl, d, 64);
            if (lane >= d) incl += u;
        }
        if (lane == 63) wtot[wid] = incl;
        __syncthreads();
        int base = 0;
        for (int w = 0; w < wid; ++w) base += wtot[w];
        incl += base;
        if (t <= SCAN_NB) bb[t] = incl - v;   // exclusive; bb[SCAN_NB] = total
        __syncthreads();
    }
    if (blockIdx.x == 0 && threadIdx.x == 0) off[N_NODES] = bb[SCAN_NB];
    __syncthreads();

    int i = blockIdx.x * 256 + threadIdx.x;
    int v = (i < N_NODES) ? cnt[i] : 0;
    int lane = threadIdx.x & 63, wid = threadIdx.x >> 6;
    int incl = v;
    for (int d = 1; d < 64; d <<= 1) {
        int u = __shfl_up(incl, d, 64);
        if (lane >= d) incl += u;
    }
    __syncthreads();
    if (lane == 63) wtot[wid] = incl;
    __syncthreads();
    int base = bb[blockIdx.x];
    for (int w = 0; w < wid; ++w) base += wtot[w];
    int excl = base + incl - v;
    if (i < N_NODES) {
        off[i] = excl; cursor[i] = excl;
        float d = (float)(v + 1);   // self-loop
        inv_sqrt[i] = rsqrtf(d);
        invdeg[i]   = 1.0f / d;
    }
}

// XCD-partitioned scatter: block = (chunk, range); blockIdx%8 -> XCD round-robin
__global__ void scatter_edges(const int* __restrict__ src, const int* __restrict__ dst,
                              const float* __restrict__ inv_sqrt,
                              int* __restrict__ cursor,
                              int2* __restrict__ edges) {
    int chunk = blockIdx.x >> 3;
    int range = blockIdx.x & 7;
    int e = chunk * 256 + threadIdx.x;
    if (e >= N_EDGES) return;
    int d = dst[e];
    int lo = range * DST_RANGE;
    if ((unsigned)(d - lo) < (unsigned)DST_RANGE) {
        int s = src[e];
        int pos = atomicAdd(&cursor[d], 1);
        float w = inv_sqrt[s] * inv_sqrt[d];
        edges[pos] = make_int2(s, __float_as_int(w));
    }
}

// ---- merged-stream gather for 4 consecutive nodes ----
// Edge range [e0,e4) is contiguous in CSR; processed as ONE pipelined stream:
// gathers for batch b+1 and edge-loads for batch b+2 in flight while
// consuming batch b. Accumulator routing uses node boundaries b1,b2,b3
// (wave-uniform): batches inside one node take the 8-fma fast path.
__device__ __forceinline__ void gather_stream4(
    const __hip_bfloat16* __restrict__ Hbf,
    const int2* __restrict__ edges,
    int e0, int b1, int b2, int b3, int e4, int j,
    float& a0, float& a1, float& a2, float& a3)
{
    int k = e0;
    int B = (e4 - e0) >> 3;

    int2 Ec[8]; float Hc[8];
    int2 En[8];

    auto ld8 = [&](int2* E, int kb) {
#pragma unroll
        for (int i = 0; i < 8; ++i) E[i] = edges[kb + i];
    };
    auto gt8 = [&](float* Hh, const int2* E) {
#pragma unroll
        for (int i = 0; i < 8; ++i)
            Hh[i] = __bfloat162float(Hbf[(size_t)E[i].x * DIM + j]);
    };
    auto consume = [&](const int2* E, const float* Hh, int kb) {
        int selA = (kb >= b1) + (kb >= b2) + (kb >= b3);
        int selB = (kb + 7 >= b1) + (kb + 7 >= b2) + (kb + 7 >= b3);
        if (selA == selB) {                 // whole batch in one node (common)
            float s = 0.f;
#pragma unroll
            for (int i = 0; i < 8; ++i)
                s = fmaf(Hh[i], __int_as_float(E[i].y), s);
            if      (selA == 0) a0 += s;
            else if (selA == 1) a1 += s;
            else if (selA == 2) a2 += s;
            else                a3 += s;
        } else {                            // boundary batch: per-edge select
#pragma unroll
            for (int i = 0; i < 8; ++i) {
                int kk = kb + i;
                float p = Hh[i] * __int_as_float(E[i].y);
                int sel = (kk >= b1) + (kk >= b2) + (kk >= b3);
                a0 += (sel == 0) ? p : 0.f;
                a1 += (sel == 1) ? p : 0.f;
                a2 += (sel == 2) ? p : 0.f;
                a3 += (sel == 3) ? p : 0.f;
            }
        }
    };

    if (B >= 2) {
        ld8(Ec, k);
        gt8(Hc, Ec);
        ld8(En, k + 8);
        for (int b = 0; b < B - 2; ++b) {
            float Hn[8];
            gt8(Hn, En);          // gathers batch b+1 in flight
            int2 Ef[8];
            ld8(Ef, k + 16);      // edge loads batch b+2 in flight
            consume(Ec, Hc, k);   // waits only on batch b gathers
#pragma unroll
            for (int i = 0; i < 8; ++i) { Ec[i] = En[i]; Hc[i] = Hn[i]; En[i] = Ef[i]; }
            k += 8;
        }
        {
            float Hn[8];
            gt8(Hn, En);
            consume(Ec, Hc, k);
#pragma unroll
            for (int i = 0; i < 8; ++i) { Ec[i] = En[i]; Hc[i] = Hn[i]; }
            k += 8;
            consume(Ec, Hc, k);
            k += 8;
        }
    } else if (B == 1) {
        ld8(Ec, k); gt8(Hc, Ec); consume(Ec, Hc, k); k += 8;
    }
    for (; k < e4; ++k) {
        int2 e = edges[k];
        float p = __bfloat162float(Hbf[(size_t)e.x * DIM + j]) * __int_as_float(e.y);
        int sel = (k >= b1) + (k >= b2) + (k >= b3);
        a0 += (sel == 0) ? p : 0.f;
        a1 += (sel == 1) ? p : 0.f;
        a2 += (sel == 2) ? p : 0.f;
        a3 += (sel == 3) ? p : 0.f;
    }
}

// ---- h = X @ W  (N x 64 @ 64 x 64); fp32 Y + bf16 copy ----
// W in NATURAL [k][j] layout in LDS (2-way alias only: free).

__global__ __launch_bounds__(256) void gemm64(const float* __restrict__ X,
                                              const float* __restrict__ W,
                                              float* __restrict__ Y,
                                              __hip_bfloat16* __restrict__ Ybf,
                                              int nrows) {
    __shared__ float Ws[64 * 64];
    for (int i = threadIdx.x; i < 64 * 64; i += 256) Ws[i] = W[i];
    __syncthreads();
    int wave = threadIdx.x >> 6;
    int j    = threadIdx.x & 63;
    int row0 = (blockIdx.x * 4 + wave) * 8;
    if (row0 >= nrows) return;
    float acc[8] = {0,0,0,0,0,0,0,0};
    const float* x0 = X + (size_t)row0 * DIM;   // wave-uniform
    int nr = (row0 + 8 <= nrows) ? 8 : (nrows - row0);
    if (nr == 8) {
#pragma unroll
        for (int k4 = 0; k4 < 16; ++k4) {
            float w0 = Ws[(4 * k4 + 0) * 64 + j];
            float w1 = Ws[(4 * k4 + 1) * 64 + j];
            float w2 = Ws[(4 * k4 + 2) * 64 + j];
            float w3 = Ws[(4 * k4 + 3) * 64 + j];
#pragma unroll
            for (int r = 0; r < 8; ++r) {
                float4 x4 = *(const float4*)&x0[r * DIM + k4 * 4];
                acc[r] = fmaf(x4.x, w0, acc[r]);
                acc[r] = fmaf(x4.y, w1, acc[r]);
                acc[r] = fmaf(x4.z, w2, acc[r]);
                acc[r] = fmaf(x4.w, w3, acc[r]);
            }
        }
    } else {
        for (int k4 = 0; k4 < 16; ++k4) {
            float w0 = Ws[(4 * k4 + 0) * 64 + j];
            float w1 = Ws[(4 * k4 + 1) * 64 + j];
            float w2 = Ws[(4 * k4 + 2) * 64 + j];
            float w3 = Ws[(4 * k4 + 3) * 64 + j];
            for (int r = 0; r < nr; ++r) {
                float4 x4 = *(const float4*)&x0[r * DIM + k4 * 4];
                acc[r] = fmaf(x4.x, w0, acc[r]);
                acc[r] = fmaf(x4.y, w1, acc[r]);
                acc[r] = fmaf(x4.z, w2, acc[r]);
                acc[r] = fmaf(x4.w, w3, acc[r]);
            }
        }
    }
    for (int r = 0; r < nr; ++r) {
        Y[(size_t)(row0 + r) * DIM + j]   = acc[r];
        Ybf[(size_t)(row0 + r) * DIM + j] = __float2bfloat16(acc[r]);
    }
}

// ---- fused: layer-1 aggregate (+bias1, relu) THEN layer-2 gemm (@W2) ----
// 16 nodes/block (4 per wave, merged-stream gather), W2 natural layout.

__global__ __launch_bounds__(256) void agg_gemm(const float* __restrict__ H,
                                                const __hip_bfloat16* __restrict__ Hbf,
                                                const int* __restrict__ off,
                                                const int2* __restrict__ edges,
                                                const float* __restrict__ invdeg,
                                                const float* __restrict__ bias,
                                                const float* __restrict__ W2,
                                                float* __restrict__ Y,
                                                __hip_bfloat16* __restrict__ Ybf2) {
    __shared__ float Ws[64 * 64];
    __shared__ float rowbuf[4][4][64];   // [wave][r][j]
    for (int i = threadIdx.x; i < 64 * 64; i += 256) Ws[i] = W2[i];
    __syncthreads();
    int wave = threadIdx.x >> 6;
    int j    = threadIdx.x & 63;
    int n0   = (blockIdx.x * 4 + wave) * 4;   // N_NODES = 16*3125: exact
    int e0 = off[n0], b1v = off[n0 + 1], b2v = off[n0 + 2], b3v = off[n0 + 3], e4 = off[n0 + 4];
    float a0 = H[(size_t)(n0 + 0) * DIM + j] * invdeg[n0 + 0];
    float a1 = H[(size_t)(n0 + 1) * DIM + j] * invdeg[n0 + 1];
    float a2 = H[(size_t)(n0 + 2) * DIM + j] * invdeg[n0 + 2];
    float a3 = H[(size_t)(n0 + 3) * DIM + j] * invdeg[n0 + 3];
    gather_stream4(Hbf, edges, e0, b1v, b2v, b3v, e4, j, a0, a1, a2, a3);
    float bj = bias[j];
    rowbuf[wave][0][j] = fmaxf(a0 + bj, 0.f);
    rowbuf[wave][1][j] = fmaxf(a1 + bj, 0.f);
    rowbuf[wave][2][j] = fmaxf(a2 + bj, 0.f);
    rowbuf[wave][3][j] = fmaxf(a3 + bj, 0.f);
    // same-wave LDS write->read: compiler inserts lgkmcnt wait; no barrier needed
    float acc2[4] = {0.f, 0.f, 0.f, 0.f};
#pragma unroll
    for (int k4 = 0; k4 < 16; ++k4) {
        float w0 = Ws[(4 * k4 + 0) * 64 + j];
        float w1 = Ws[(4 * k4 + 1) * 64 + j];
        float w2 = Ws[(4 * k4 + 2) * 64 + j];
        float w3 = Ws[(4 * k4 + 3) * 64 + j];
#pragma unroll
        for (int r = 0; r < 4; ++r) {
            float4 h4 = *(const float4*)&rowbuf[wave][r][k4 * 4];  // broadcast: free
            acc2[r] = fmaf(h4.x, w0, acc2[r]);
            acc2[r] = fmaf(h4.y, w1, acc2[r]);
            acc2[r] = fmaf(h4.z, w2, acc2[r]);
            acc2[r] = fmaf(h4.w, w3, acc2[r]);
        }
    }
#pragma unroll
    for (int r = 0; r < 4; ++r) {
        int node = n0 + r;
        Y[(size_t)node * DIM + j]    = acc2[r];
        Ybf2[(size_t)node * DIM + j] = __float2bfloat16(acc2[r]);
    }
}

// ---- layer-2 aggregate (+bias2, relu), merged-stream gather ----

__global__ __launch_bounds__(256) void aggregate(const float* __restrict__ H,
                                                 const __hip_bfloat16* __restrict__ Hbf,
                                                 const int* __restrict__ off,
                                                 const int2* __restrict__ edges,
                                                 const float* __restrict__ invdeg,
                                                 const float* __restrict__ bias,
                                                 float* __restrict__ Y) {
    int wave = threadIdx.x >> 6;
    int j    = threadIdx.x & 63;
    int n0   = (blockIdx.x * 4 + wave) * 4;   // exact
    int e0 = off[n0], b1v = off[n0 + 1], b2v = off[n0 + 2], b3v = off[n0 + 3], e4 = off[n0 + 4];
    float a0 = H[(size_t)(n0 + 0) * DIM + j] * invdeg[n0 + 0];
    float a1 = H[(size_t)(n0 + 1) * DIM + j] * invdeg[n0 + 1];
    float a2 = H[(size_t)(n0 + 2) * DIM + j] * invdeg[n0 + 2];
    float a3 = H[(size_t)(n0 + 3) * DIM + j] * invdeg[n0 + 3];
    gather_stream4(Hbf, edges, e0, b1v, b2v, b3v, e4, j, a0, a1, a2, a3);
    float bj = bias[j];
    Y[(size_t)(n0 + 0) * DIM + j] = fmaxf(a0 + bj, 0.f);
    Y[(size_t)(n0 + 1) * DIM + j] = fmaxf(a1 + bj, 0.f);
    Y[(size_t)(n0 + 2) * DIM + j] = fmaxf(a2 + bj, 0.f);
    Y[(size_t)(n0 + 3) * DIM + j] = fmaxf(a3 + bj, 0.f);
}

// ---- fused mean-pool + FC: one block per graph, batch is sorted ----

__global__ __launch_bounds__(256) void pool_fc(const float* __restrict__ H,
                                               const int* __restrict__ batch,
                                               const float* __restrict__ fcW,
                                               const float* __restrict__ fcb,
                                               float* __restrict__ out) {
    __shared__ float part[4][64];
    __shared__ float mean[64];
    int g = blockIdx.x;
    int lo = 0, hi = N_NODES;
    while (lo < hi) { int mid = (lo + hi) >> 1; if (batch[mid] < g) lo = mid + 1; else hi = mid; }
    int start = lo;
    hi = N_NODES;
    while (lo < hi) { int mid = (lo + hi) >> 1; if (batch[mid] < g + 1) lo = mid + 1; else hi = mid; }
    int end = lo;

    int wave = threadIdx.x >> 6, j = threadIdx.x & 63;
    float acc = 0.f;
    for (int n = start + wave; n < end; n += 4)
        acc += H[(size_t)n * DIM + j];
    part[wave][j] = acc;
    __syncthreads();
    if (wave == 0) {
        float s = part[0][j] + part[1][j] + part[2][j] + part[3][j];
        mean[j] = s / fmaxf((float)(end - start), 1.0f);
    }
    __syncthreads();
    if (threadIdx.x < ODIM) {
        int jj = threadIdx.x;
        float a = fcb[jj];
#pragma unroll
        for (int k = 0; k < DIM; ++k) a = fmaf(mean[k], fcW[k * ODIM + jj], a);
        out[g * ODIM + jj] = a;
    }
}

extern "C" void kernel_launch(void* const* d_in, const int* in_sizes, int n_in,
                              void* d_out, int out_size, void* d_ws, size_t ws_size,
                              hipStream_t stream) {
    const float* x    = (const float*)d_in[0];
    const float* W1   = (const float*)d_in[1];
    const float* b1   = (const float*)d_in[2];
    const float* W2   = (const float*)d_in[3];
    const float* b2   = (const float*)d_in[4];
    const float* fcW  = (const float*)d_in[5];
    const float* fcb  = (const float*)d_in[6];
    const int*   eidx = (const int*)d_in[7];
    const int*   batch= (const int*)d_in[8];
    const int* esrc = eidx;
    const int* edst = eidx + N_EDGES;
    float* out = (float*)d_out;

    char* ws = (char*)d_ws;
    size_t o = 0;
    auto alloc = [&](size_t bytes) {
        void* p = ws + o;
        o += (bytes + 255) & ~(size_t)255;
        return p;
    };
    float* bufA     = (float*)alloc((size_t)N_NODES * DIM * 4);
    float* bufB     = (float*)alloc((size_t)N_NODES * DIM * 4);
    __hip_bfloat16* bf1 = (__hip_bfloat16*)alloc((size_t)N_NODES * DIM * 2);
    __hip_bfloat16* bf2 = (__hip_bfloat16*)alloc((size_t)N_NODES * DIM * 2);
    int*   cnt      = (int*)  alloc((size_t)N_NODES * 4);
    int*   off      = (int*)  alloc((size_t)(N_NODES + 1) * 4);
    int*   cursor   = (int*)  alloc((size_t)N_NODES * 4);
    float* inv_sqrt = (float*)alloc((size_t)N_NODES * 4);
    float* invdeg   = (float*)alloc((size_t)N_NODES * 4);
    int2*  edges    = (int2*) alloc((size_t)N_EDGES * 8);
    int*   blocksum = (int*)  alloc((size_t)SCAN_NB * 4);

    hipMemsetAsync(cnt, 0, (size_t)N_NODES * 4, stream);

    count_deg<<<(N_EDGES + 255) / 256, 256, 0, stream>>>(edst, cnt);
    scan_p1<<<SCAN_NB, 256, 0, stream>>>(cnt, blocksum);
    scan_p3<<<SCAN_NB, 256, 0, stream>>>(cnt, blocksum, off, cursor, inv_sqrt, invdeg);
    scatter_edges<<<((N_EDGES + 255) / 256) * NXCD, 256, 0, stream>>>(esrc, edst, inv_sqrt, cursor, edges);

    gemm64<<<(N_NODES + 31) / 32, 256, 0, stream>>>(x, W1, bufA, bf1, N_NODES);
    agg_gemm<<<N_NODES / 16, 256, 0, stream>>>(bufA, bf1, off, edges, invdeg, b1, W2, bufB, bf2);
    aggregate<<<N_NODES / 16, 256, 0, stream>>>(bufB, bf2, off, edges, invdeg, b2, bufA);

    pool_fc<<<N_GRAPHS, 256, 0, stream>>>(bufA, batch, fcW, fcb, out);
}

// Round 14
// 297.006 us; speedup vs baseline: 1.0301x; 1.0086x over previous
//
#include <hip/hip_runtime.h>
#include <hip/hip_bf16.h>

#define N_NODES 50000
#define N_EDGES 800000
#define DIM 64
#define ODIM 32
#define N_GRAPHS 512
#define SCAN_NB ((N_NODES + 255) / 256)   // 196
#define NXCD 8
#define DST_RANGE ((N_NODES + NXCD - 1) / NXCD)   // 6250

// ---- graph prep: counting-sort edges by dst into CSR ----

__global__ void count_deg(const int* __restrict__ dst, int* __restrict__ cnt) {
    int e = blockIdx.x * blockDim.x + threadIdx.x;
    if (e < N_EDGES) atomicAdd(&cnt[__builtin_nontemporal_load(&dst[e])], 1);
}

// ---- 2-phase exclusive scan over cnt[N_NODES] ----

__global__ __launch_bounds__(256) void scan_p1(const int* __restrict__ cnt,
                                               int* __restrict__ blocksum) {
    __shared__ int ws[4];
    int i = blockIdx.x * 256 + threadIdx.x;
    int v = (i < N_NODES) ? cnt[i] : 0;
    for (int d = 32; d > 0; d >>= 1) v += __shfl_down(v, d, 64);
    int lane = threadIdx.x & 63, wid = threadIdx.x >> 6;
    if (lane == 0) ws[wid] = v;
    __syncthreads();
    if (threadIdx.x == 0) blocksum[blockIdx.x] = ws[0] + ws[1] + ws[2] + ws[3];
}

__global__ __launch_bounds__(256) void scan_p3(const int* __restrict__ cnt,
                                               const int* __restrict__ blocksum,
                                               int* __restrict__ off,
                                               int* __restrict__ cursor,
                                               float* __restrict__ inv_sqrt,
                                               float* __restrict__ invdeg) {
    __shared__ int wtot[4];
    __shared__ int bb[SCAN_NB + 1];
    {
        int t = threadIdx.x;
        int v = (t < SCAN_NB) ? blocksum[t] : 0;
        int lane = t & 63, wid = t >> 6;
        int incl = v;
        for (int d = 1; d < 64; d <<= 1) {
            int u = __shfl_up(incl, d, 64);
            if (lane >= d) incl += u;
        }
        if (lane == 63) wtot[wid] = incl;
        __syncthreads();
        int base = 0;
        for (int w = 0; w < wid; ++w) base += wtot[w];
        incl += base;
        if (t <= SCAN_NB) bb[t] = incl - v;   // exclusive; bb[SCAN_NB] = total
        __syncthreads();
    }
    if (blockIdx.x == 0 && threadIdx.x == 0) off[N_NODES] = bb[SCAN_NB];
    __syncthreads();

    int i = blockIdx.x * 256 + threadIdx.x;
    int v = (i < N_NODES) ? cnt[i] : 0;
    int lane = threadIdx.x & 63, wid = threadIdx.x >> 6;
    int incl = v;
    for (int d = 1; d < 64; d <<= 1) {
        int u = __shfl_up(incl, d, 64);
        if (lane >= d) incl += u;
    }
    __syncthreads();
    if (lane == 63) wtot[wid] = incl;
    __syncthreads();
    int base = bb[blockIdx.x];
    for (int w = 0; w < wid; ++w) base += wtot[w];
    int excl = base + incl - v;
    if (i < N_NODES) {
        off[i] = excl; cursor[i] = excl;
        float d = (float)(v + 1);   // self-loop
        inv_sqrt[i] = rsqrtf(d);
        invdeg[i]   = 1.0f / d;
    }
}

// XCD-partitioned scatter: block = (chunk, range); blockIdx%8 -> XCD round-robin
__global__ void scatter_edges(const int* __restrict__ src, const int* __restrict__ dst,
                              const float* __restrict__ inv_sqrt,
                              int* __restrict__ cursor,
                              int2* __restrict__ edges) {
    int chunk = blockIdx.x >> 3;
    int range = blockIdx.x & 7;
    int e = chunk * 256 + threadIdx.x;
    if (e >= N_EDGES) return;
    int d = dst[e];
    int lo = range * DST_RANGE;
    if ((unsigned)(d - lo) < (unsigned)DST_RANGE) {
        int s = src[e];
        int pos = atomicAdd(&cursor[d], 1);
        float w = inv_sqrt[s] * inv_sqrt[d];
        edges[pos] = make_int2(s, __float_as_int(w));
    }
}

// ---- merged-stream gather for 4 consecutive nodes (see R13 notes) ----
__device__ __forceinline__ void gather_stream4(
    const __hip_bfloat16* __restrict__ Hbf,
    const int2* __restrict__ edges,
    int e0, int b1, int b2, int b3, int e4, int j,
    float& a0, float& a1, float& a2, float& a3)
{
    int k = e0;
    int B = (e4 - e0) >> 3;

    int2 Ec[8]; float Hc[8];
    int2 En[8];

    auto ld8 = [&](int2* E, int kb) {
#pragma unroll
        for (int i = 0; i < 8; ++i) E[i] = edges[kb + i];
    };
    auto gt8 = [&](float* Hh, const int2* E) {
#pragma unroll
        for (int i = 0; i < 8; ++i)
            Hh[i] = __bfloat162float(Hbf[(size_t)E[i].x * DIM + j]);
    };
    auto consume = [&](const int2* E, const float* Hh, int kb) {
        int selA = (kb >= b1) + (kb >= b2) + (kb >= b3);
        int selB = (kb + 7 >= b1) + (kb + 7 >= b2) + (kb + 7 >= b3);
        if (selA == selB) {                 // whole batch in one node (common)
            float s = 0.f;
#pragma unroll
            for (int i = 0; i < 8; ++i)
                s = fmaf(Hh[i], __int_as_float(E[i].y), s);
            if      (selA == 0) a0 += s;
            else if (selA == 1) a1 += s;
            else if (selA == 2) a2 += s;
            else                a3 += s;
        } else {                            // boundary batch: per-edge select
#pragma unroll
            for (int i = 0; i < 8; ++i) {
                int kk = kb + i;
                float p = Hh[i] * __int_as_float(E[i].y);
                int sel = (kk >= b1) + (kk >= b2) + (kk >= b3);
                a0 += (sel == 0) ? p : 0.f;
                a1 += (sel == 1) ? p : 0.f;
                a2 += (sel == 2) ? p : 0.f;
                a3 += (sel == 3) ? p : 0.f;
            }
        }
    };

    if (B >= 2) {
        ld8(Ec, k);
        gt8(Hc, Ec);
        ld8(En, k + 8);
        for (int b = 0; b < B - 2; ++b) {
            float Hn[8];
            gt8(Hn, En);          // gathers batch b+1 in flight
            int2 Ef[8];
            ld8(Ef, k + 16);      // edge loads batch b+2 in flight
            consume(Ec, Hc, k);   // waits only on batch b gathers
#pragma unroll
            for (int i = 0; i < 8; ++i) { Ec[i] = En[i]; Hc[i] = Hn[i]; En[i] = Ef[i]; }
            k += 8;
        }
        {
            float Hn[8];
            gt8(Hn, En);
            consume(Ec, Hc, k);
#pragma unroll
            for (int i = 0; i < 8; ++i) { Ec[i] = En[i]; Hc[i] = Hn[i]; }
            k += 8;
            consume(Ec, Hc, k);
            k += 8;
        }
    } else if (B == 1) {
        ld8(Ec, k); gt8(Hc, Ec); consume(Ec, Hc, k); k += 8;
    }
    for (; k < e4; ++k) {
        int2 e = edges[k];
        float p = __bfloat162float(Hbf[(size_t)e.x * DIM + j]) * __int_as_float(e.y);
        int sel = (k >= b1) + (k >= b2) + (k >= b3);
        a0 += (sel == 0) ? p : 0.f;
        a1 += (sel == 1) ? p : 0.f;
        a2 += (sel == 2) ? p : 0.f;
        a3 += (sel == 3) ? p : 0.f;
    }
}

// ---- h = X @ W  (N x 64 @ 64 x 64); bf16 output only ----
// W in NATURAL [k][j] layout in LDS (2-way alias only: free).

__global__ __launch_bounds__(256) void gemm64(const float* __restrict__ X,
                                              const float* __restrict__ W,
                                              __hip_bfloat16* __restrict__ Ybf,
                                              int nrows) {
    __shared__ float Ws[64 * 64];
    for (int i = threadIdx.x; i < 64 * 64; i += 256) Ws[i] = W[i];
    __syncthreads();
    int wave = threadIdx.x >> 6;
    int j    = threadIdx.x & 63;
    int row0 = (blockIdx.x * 4 + wave) * 8;
    if (row0 >= nrows) return;
    float acc[8] = {0,0,0,0,0,0,0,0};
    const float* x0 = X + (size_t)row0 * DIM;   // wave-uniform
    int nr = (row0 + 8 <= nrows) ? 8 : (nrows - row0);
    if (nr == 8) {
#pragma unroll
        for (int k4 = 0; k4 < 16; ++k4) {
            float w0 = Ws[(4 * k4 + 0) * 64 + j];
            float w1 = Ws[(4 * k4 + 1) * 64 + j];
            float w2 = Ws[(4 * k4 + 2) * 64 + j];
            float w3 = Ws[(4 * k4 + 3) * 64 + j];
#pragma unroll
            for (int r = 0; r < 8; ++r) {
                float4 x4 = *(const float4*)&x0[r * DIM + k4 * 4];
                acc[r] = fmaf(x4.x, w0, acc[r]);
                acc[r] = fmaf(x4.y, w1, acc[r]);
                acc[r] = fmaf(x4.z, w2, acc[r]);
                acc[r] = fmaf(x4.w, w3, acc[r]);
            }
        }
    } else {
        for (int k4 = 0; k4 < 16; ++k4) {
            float w0 = Ws[(4 * k4 + 0) * 64 + j];
            float w1 = Ws[(4 * k4 + 1) * 64 + j];
            float w2 = Ws[(4 * k4 + 2) * 64 + j];
            float w3 = Ws[(4 * k4 + 3) * 64 + j];
            for (int r = 0; r < nr; ++r) {
                float4 x4 = *(const float4*)&x0[r * DIM + k4 * 4];
                acc[r] = fmaf(x4.x, w0, acc[r]);
                acc[r] = fmaf(x4.y, w1, acc[r]);
                acc[r] = fmaf(x4.z, w2, acc[r]);
                acc[r] = fmaf(x4.w, w3, acc[r]);
            }
        }
    }
    for (int r = 0; r < nr; ++r)
        Ybf[(size_t)(row0 + r) * DIM + j] = __float2bfloat16(acc[r]);
}

// ---- fused: layer-1 aggregate (+bias1, relu) THEN layer-2 gemm (@W2) ----
// Self-term from bf16 (errors pooled away downstream); bf16 output only.

__global__ __launch_bounds__(256) void agg_gemm(const __hip_bfloat16* __restrict__ Hbf,
                                                const int* __restrict__ off,
                                                const int2* __restrict__ edges,
                                                const float* __restrict__ invdeg,
                                                const float* __restrict__ bias,
                                                const float* __restrict__ W2,
                                                __hip_bfloat16* __restrict__ Ybf2) {
    __shared__ float Ws[64 * 64];
    __shared__ float rowbuf[4][4][64];   // [wave][r][j]
    for (int i = threadIdx.x; i < 64 * 64; i += 256) Ws[i] = W2[i];
    __syncthreads();
    int wave = threadIdx.x >> 6;
    int j    = threadIdx.x & 63;
    int n0   = (blockIdx.x * 4 + wave) * 4;   // N_NODES = 16*3125: exact
    int e0 = off[n0], b1v = off[n0 + 1], b2v = off[n0 + 2], b3v = off[n0 + 3], e4 = off[n0 + 4];
    float a0 = __bfloat162float(Hbf[(size_t)(n0 + 0) * DIM + j]) * invdeg[n0 + 0];
    float a1 = __bfloat162float(Hbf[(size_t)(n0 + 1) * DIM + j]) * invdeg[n0 + 1];
    float a2 = __bfloat162float(Hbf[(size_t)(n0 + 2) * DIM + j]) * invdeg[n0 + 2];
    float a3 = __bfloat162float(Hbf[(size_t)(n0 + 3) * DIM + j]) * invdeg[n0 + 3];
    gather_stream4(Hbf, edges, e0, b1v, b2v, b3v, e4, j, a0, a1, a2, a3);
    float bj = bias[j];
    rowbuf[wave][0][j] = fmaxf(a0 + bj, 0.f);
    rowbuf[wave][1][j] = fmaxf(a1 + bj, 0.f);
    rowbuf[wave][2][j] = fmaxf(a2 + bj, 0.f);
    rowbuf[wave][3][j] = fmaxf(a3 + bj, 0.f);
    // same-wave LDS write->read: compiler inserts lgkmcnt wait; no barrier needed
    float acc2[4] = {0.f, 0.f, 0.f, 0.f};
#pragma unroll
    for (int k4 = 0; k4 < 16; ++k4) {
        float w0 = Ws[(4 * k4 + 0) * 64 + j];
        float w1 = Ws[(4 * k4 + 1) * 64 + j];
        float w2 = Ws[(4 * k4 + 2) * 64 + j];
        float w3 = Ws[(4 * k4 + 3) * 64 + j];
#pragma unroll
        for (int r = 0; r < 4; ++r) {
            float4 h4 = *(const float4*)&rowbuf[wave][r][k4 * 4];  // broadcast: free
            acc2[r] = fmaf(h4.x, w0, acc2[r]);
            acc2[r] = fmaf(h4.y, w1, acc2[r]);
            acc2[r] = fmaf(h4.z, w2, acc2[r]);
            acc2[r] = fmaf(h4.w, w3, acc2[r]);
        }
    }
#pragma unroll
    for (int r = 0; r < 4; ++r)
        Ybf2[(size_t)(n0 + r) * DIM + j] = __float2bfloat16(acc2[r]);
}

// ---- layer-2 aggregate (+bias2, relu), self-term bf16, fp32 out for pool ----

__global__ __launch_bounds__(256) void aggregate(const __hip_bfloat16* __restrict__ Hbf,
                                                 const int* __restrict__ off,
                                                 const int2* __restrict__ edges,
                                                 const float* __restrict__ invdeg,
                                                 const float* __restrict__ bias,
                                                 float* __restrict__ Y) {
    int wave = threadIdx.x >> 6;
    int j    = threadIdx.x & 63;
    int n0   = (blockIdx.x * 4 + wave) * 4;   // exact
    int e0 = off[n0], b1v = off[n0 + 1], b2v = off[n0 + 2], b3v = off[n0 + 3], e4 = off[n0 + 4];
    float a0 = __bfloat162float(Hbf[(size_t)(n0 + 0) * DIM + j]) * invdeg[n0 + 0];
    float a1 = __bfloat162float(Hbf[(size_t)(n0 + 1) * DIM + j]) * invdeg[n0 + 1];
    float a2 = __bfloat162float(Hbf[(size_t)(n0 + 2) * DIM + j]) * invdeg[n0 + 2];
    float a3 = __bfloat162float(Hbf[(size_t)(n0 + 3) * DIM + j]) * invdeg[n0 + 3];
    gather_stream4(Hbf, edges, e0, b1v, b2v, b3v, e4, j, a0, a1, a2, a3);
    float bj = bias[j];
    Y[(size_t)(n0 + 0) * DIM + j] = fmaxf(a0 + bj, 0.f);
    Y[(size_t)(n0 + 1) * DIM + j] = fmaxf(a1 + bj, 0.f);
    Y[(size_t)(n0 + 2) * DIM + j] = fmaxf(a2 + bj, 0.f);
    Y[(size_t)(n0 + 3) * DIM + j] = fmaxf(a3 + bj, 0.f);
}

// ---- fused mean-pool + FC: one block per graph, batch is sorted ----

__global__ __launch_bounds__(256) void pool_fc(const float* __restrict__ H,
                                               const int* __restrict__ batch,
                                               const float* __restrict__ fcW,
                                               const float* __restrict__ fcb,
                                               float* __restrict__ out) {
    __shared__ float part[4][64];
    __shared__ float mean[64];
    int g = blockIdx.x;
    int lo = 0, hi = N_NODES;
    while (lo < hi) { int mid = (lo + hi) >> 1; if (batch[mid] < g) lo = mid + 1; else hi = mid; }
    int start = lo;
    hi = N_NODES;
    while (lo < hi) { int mid = (lo + hi) >> 1; if (batch[mid] < g + 1) lo = mid + 1; else hi = mid; }
    int end = lo;

    int wave = threadIdx.x >> 6, j = threadIdx.x & 63;
    float acc = 0.f;
    for (int n = start + wave; n < end; n += 4)
        acc += H[(size_t)n * DIM + j];
    part[wave][j] = acc;
    __syncthreads();
    if (wave == 0) {
        float s = part[0][j] + part[1][j] + part[2][j] + part[3][j];
        mean[j] = s / fmaxf((float)(end - start), 1.0f);
    }
    __syncthreads();
    if (threadIdx.x < ODIM) {
        int jj = threadIdx.x;
        float a = fcb[jj];
#pragma unroll
        for (int k = 0; k < DIM; ++k) a = fmaf(mean[k], fcW[k * ODIM + jj], a);
        out[g * ODIM + jj] = a;
    }
}

extern "C" void kernel_launch(void* const* d_in, const int* in_sizes, int n_in,
                              void* d_out, int out_size, void* d_ws, size_t ws_size,
                              hipStream_t stream) {
    const float* x    = (const float*)d_in[0];
    const float* W1   = (const float*)d_in[1];
    const float* b1   = (const float*)d_in[2];
    const float* W2   = (const float*)d_in[3];
    const float* b2   = (const float*)d_in[4];
    const float* fcW  = (const float*)d_in[5];
    const float* fcb  = (const float*)d_in[6];
    const int*   eidx = (const int*)d_in[7];
    const int*   batch= (const int*)d_in[8];
    const int* esrc = eidx;
    const int* edst = eidx + N_EDGES;
    float* out = (float*)d_out;

    char* ws = (char*)d_ws;
    size_t o = 0;
    auto alloc = [&](size_t bytes) {
        void* p = ws + o;
        o += (bytes + 255) & ~(size_t)255;
        return p;
    };
    float* bufA     = (float*)alloc((size_t)N_NODES * DIM * 4);
    __hip_bfloat16* bf1 = (__hip_bfloat16*)alloc((size_t)N_NODES * DIM * 2);
    __hip_bfloat16* bf2 = (__hip_bfloat16*)alloc((size_t)N_NODES * DIM * 2);
    int*   cnt      = (int*)  alloc((size_t)N_NODES * 4);
    int*   off      = (int*)  alloc((size_t)(N_NODES + 1) * 4);
    int*   cursor   = (int*)  alloc((size_t)N_NODES * 4);
    float* inv_sqrt = (float*)alloc((size_t)N_NODES * 4);
    float* invdeg   = (float*)alloc((size_t)N_NODES * 4);
    int2*  edges    = (int2*) alloc((size_t)N_EDGES * 8);
    int*   blocksum = (int*)  alloc((size_t)SCAN_NB * 4);

    hipMemsetAsync(cnt, 0, (size_t)N_NODES * 4, stream);

    count_deg<<<(N_EDGES + 255) / 256, 256, 0, stream>>>(edst, cnt);
    scan_p1<<<SCAN_NB, 256, 0, stream>>>(cnt, blocksum);
    scan_p3<<<SCAN_NB, 256, 0, stream>>>(cnt, blocksum, off, cursor, inv_sqrt, invdeg);
    scatter_edges<<<((N_EDGES + 255) / 256) * NXCD, 256, 0, stream>>>(esrc, edst, inv_sqrt, cursor, edges);

    gemm64<<<(N_NODES + 31) / 32, 256, 0, stream>>>(x, W1, bf1, N_NODES);
    agg_gemm<<<N_NODES / 16, 256, 0, stream>>>(bf1, off, edges, invdeg, b1, W2, bf2);
    aggregate<<<N_NODES / 16, 256, 0, stream>>>(bf2, off, edges, invdeg, b2, bufA);

    pool_fc<<<N_GRAPHS, 256, 0, stream>>>(bufA, batch, fcW, fcb, out);
}

// Round 15
// 288.907 us; speedup vs baseline: 1.0590x; 1.0280x over previous
//
#include <hip/hip_runtime.h>
#include <hip/hip_bf16.h>

#define N_NODES 50000
#define N_EDGES 800000
#define DIM 64
#define ODIM 32
#define N_GRAPHS 512
#define SCAN_NB ((N_NODES + 255) / 256)   // 196
#define NXCD 8
#define DST_RANGE ((N_NODES + NXCD - 1) / NXCD)   // 6250

// ---- graph prep: counting-sort edges by dst into CSR ----

__global__ void count_deg(const int* __restrict__ dst, int* __restrict__ cnt) {
    int e = blockIdx.x * blockDim.x + threadIdx.x;
    if (e < N_EDGES) atomicAdd(&cnt[__builtin_nontemporal_load(&dst[e])], 1);
}

// ---- 2-phase exclusive scan over cnt[N_NODES] ----

__global__ __launch_bounds__(256) void scan_p1(const int* __restrict__ cnt,
                                               int* __restrict__ blocksum) {
    __shared__ int ws[4];
    int i = blockIdx.x * 256 + threadIdx.x;
    int v = (i < N_NODES) ? cnt[i] : 0;
    for (int d = 32; d > 0; d >>= 1) v += __shfl_down(v, d, 64);
    int lane = threadIdx.x & 63, wid = threadIdx.x >> 6;
    if (lane == 0) ws[wid] = v;
    __syncthreads();
    if (threadIdx.x == 0) blocksum[blockIdx.x] = ws[0] + ws[1] + ws[2] + ws[3];
}

__global__ __launch_bounds__(256) void scan_p3(const int* __restrict__ cnt,
                                               const int* __restrict__ blocksum,
                                               int* __restrict__ off,
                                               int* __restrict__ cursor,
                                               float* __restrict__ inv_sqrt,
                                               float* __restrict__ invdeg) {
    __shared__ int wtot[4];
    __shared__ int bb[SCAN_NB + 1];
    {
        int t = threadIdx.x;
        int v = (t < SCAN_NB) ? blocksum[t] : 0;
        int lane = t & 63, wid = t >> 6;
        int incl = v;
        for (int d = 1; d < 64; d <<= 1) {
            int u = __shfl_up(incl, d, 64);
            if (lane >= d) incl += u;
        }
        if (lane == 63) wtot[wid] = incl;
        __syncthreads();
        int base = 0;
        for (int w = 0; w < wid; ++w) base += wtot[w];
        incl += base;
        if (t <= SCAN_NB) bb[t] = incl - v;   // exclusive; bb[SCAN_NB] = total
        __syncthreads();
    }
    if (blockIdx.x == 0 && threadIdx.x == 0) off[N_NODES] = bb[SCAN_NB];
    __syncthreads();

    int i = blockIdx.x * 256 + threadIdx.x;
    int v = (i < N_NODES) ? cnt[i] : 0;
    int lane = threadIdx.x & 63, wid = threadIdx.x >> 6;
    int incl = v;
    for (int d = 1; d < 64; d <<= 1) {
        int u = __shfl_up(incl, d, 64);
        if (lane >= d) incl += u;
    }
    __syncthreads();
    if (lane == 63) wtot[wid] = incl;
    __syncthreads();
    int base = bb[blockIdx.x];
    for (int w = 0; w < wid; ++w) base += wtot[w];
    int excl = base + incl - v;
    if (i < N_NODES) {
        off[i] = excl; cursor[i] = excl;
        float d = (float)(v + 1);   // self-loop
        inv_sqrt[i] = rsqrtf(d);
        invdeg[i]   = 1.0f / d;
    }
}

// XCD-partitioned scatter: block = (chunk, range); blockIdx%8 -> XCD round-robin
__global__ void scatter_edges(const int* __restrict__ src, const int* __restrict__ dst,
                              const float* __restrict__ inv_sqrt,
                              int* __restrict__ cursor,
                              int2* __restrict__ edges) {
    int chunk = blockIdx.x >> 3;
    int range = blockIdx.x & 7;
    int e = chunk * 256 + threadIdx.x;
    if (e >= N_EDGES) return;
    int d = dst[e];
    int lo = range * DST_RANGE;
    if ((unsigned)(d - lo) < (unsigned)DST_RANGE) {
        int s = src[e];
        int pos = atomicAdd(&cursor[d], 1);
        float w = inv_sqrt[s] * inv_sqrt[d];
        edges[pos] = make_int2(s, __float_as_int(w));
    }
}

// ---- merged-stream gather for 4 consecutive nodes (see R13 notes) ----
__device__ __forceinline__ void gather_stream4(
    const __hip_bfloat16* __restrict__ Hbf,
    const int2* __restrict__ edges,
    int e0, int b1, int b2, int b3, int e4, int j,
    float& a0, float& a1, float& a2, float& a3)
{
    int k = e0;
    int B = (e4 - e0) >> 3;

    int2 Ec[8]; float Hc[8];
    int2 En[8];

    auto ld8 = [&](int2* E, int kb) {
#pragma unroll
        for (int i = 0; i < 8; ++i) E[i] = edges[kb + i];
    };
    auto gt8 = [&](float* Hh, const int2* E) {
#pragma unroll
        for (int i = 0; i < 8; ++i)
            Hh[i] = __bfloat162float(Hbf[(size_t)E[i].x * DIM + j]);
    };
    auto consume = [&](const int2* E, const float* Hh, int kb) {
        int selA = (kb >= b1) + (kb >= b2) + (kb >= b3);
        int selB = (kb + 7 >= b1) + (kb + 7 >= b2) + (kb + 7 >= b3);
        if (selA == selB) {                 // whole batch in one node (common)
            float s = 0.f;
#pragma unroll
            for (int i = 0; i < 8; ++i)
                s = fmaf(Hh[i], __int_as_float(E[i].y), s);
            if      (selA == 0) a0 += s;
            else if (selA == 1) a1 += s;
            else if (selA == 2) a2 += s;
            else                a3 += s;
        } else {                            // boundary batch: per-edge select
#pragma unroll
            for (int i = 0; i < 8; ++i) {
                int kk = kb + i;
                float p = Hh[i] * __int_as_float(E[i].y);
                int sel = (kk >= b1) + (kk >= b2) + (kk >= b3);
                a0 += (sel == 0) ? p : 0.f;
                a1 += (sel == 1) ? p : 0.f;
                a2 += (sel == 2) ? p : 0.f;
                a3 += (sel == 3) ? p : 0.f;
            }
        }
    };

    if (B >= 2) {
        ld8(Ec, k);
        gt8(Hc, Ec);
        ld8(En, k + 8);
        for (int b = 0; b < B - 2; ++b) {
            float Hn[8];
            gt8(Hn, En);          // gathers batch b+1 in flight
            int2 Ef[8];
            ld8(Ef, k + 16);      // edge loads batch b+2 in flight
            consume(Ec, Hc, k);   // waits only on batch b gathers
#pragma unroll
            for (int i = 0; i < 8; ++i) { Ec[i] = En[i]; Hc[i] = Hn[i]; En[i] = Ef[i]; }
            k += 8;
        }
        {
            float Hn[8];
            gt8(Hn, En);
            consume(Ec, Hc, k);
#pragma unroll
            for (int i = 0; i < 8; ++i) { Ec[i] = En[i]; Hc[i] = Hn[i]; }
            k += 8;
            consume(Ec, Hc, k);
            k += 8;
        }
    } else if (B == 1) {
        ld8(Ec, k); gt8(Hc, Ec); consume(Ec, Hc, k); k += 8;
    }
    for (; k < e4; ++k) {
        int2 e = edges[k];
        float p = __bfloat162float(Hbf[(size_t)e.x * DIM + j]) * __int_as_float(e.y);
        int sel = (k >= b1) + (k >= b2) + (k >= b3);
        a0 += (sel == 0) ? p : 0.f;
        a1 += (sel == 1) ? p : 0.f;
        a2 += (sel == 2) ? p : 0.f;
        a3 += (sel == 3) ? p : 0.f;
    }
}

// ---- h = X @ W  (N x 64 @ 64 x 64); bf16 output only ----
// W in NATURAL [k][j] layout in LDS (2-way alias only: free).

__global__ __launch_bounds__(256) void gemm64(const float* __restrict__ X,
                                              const float* __restrict__ W,
                                              __hip_bfloat16* __restrict__ Ybf,
                                              int nrows) {
    __shared__ float Ws[64 * 64];
    for (int i = threadIdx.x; i < 64 * 64; i += 256) Ws[i] = W[i];
    __syncthreads();
    int wave = threadIdx.x >> 6;
    int j    = threadIdx.x & 63;
    int row0 = (blockIdx.x * 4 + wave) * 8;
    if (row0 >= nrows) return;
    float acc[8] = {0,0,0,0,0,0,0,0};
    const float* x0 = X + (size_t)row0 * DIM;   // wave-uniform
    int nr = (row0 + 8 <= nrows) ? 8 : (nrows - row0);
    if (nr == 8) {
#pragma unroll
        for (int k4 = 0; k4 < 16; ++k4) {
            float w0 = Ws[(4 * k4 + 0) * 64 + j];
            float w1 = Ws[(4 * k4 + 1) * 64 + j];
            float w2 = Ws[(4 * k4 + 2) * 64 + j];
            float w3 = Ws[(4 * k4 + 3) * 64 + j];
#pragma unroll
            for (int r = 0; r < 8; ++r) {
                float4 x4 = *(const float4*)&x0[r * DIM + k4 * 4];
                acc[r] = fmaf(x4.x, w0, acc[r]);
                acc[r] = fmaf(x4.y, w1, acc[r]);
                acc[r] = fmaf(x4.z, w2, acc[r]);
                acc[r] = fmaf(x4.w, w3, acc[r]);
            }
        }
    } else {
        for (int k4 = 0; k4 < 16; ++k4) {
            float w0 = Ws[(4 * k4 + 0) * 64 + j];
            float w1 = Ws[(4 * k4 + 1) * 64 + j];
            float w2 = Ws[(4 * k4 + 2) * 64 + j];
            float w3 = Ws[(4 * k4 + 3) * 64 + j];
            for (int r = 0; r < nr; ++r) {
                float4 x4 = *(const float4*)&x0[r * DIM + k4 * 4];
                acc[r] = fmaf(x4.x, w0, acc[r]);
                acc[r] = fmaf(x4.y, w1, acc[r]);
                acc[r] = fmaf(x4.z, w2, acc[r]);
                acc[r] = fmaf(x4.w, w3, acc[r]);
            }
        }
    }
    for (int r = 0; r < nr; ++r)
        Ybf[(size_t)(row0 + r) * DIM + j] = __float2bfloat16(acc[r]);
}

// ---- fused: layer-1 aggregate (+bias1, relu) THEN layer-2 gemm (@W2) ----
// Self-term from bf16 (errors pooled away downstream); bf16 output only.

__global__ __launch_bounds__(256) void agg_gemm(const __hip_bfloat16* __restrict__ Hbf,
                                                const int* __restrict__ off,
                                                const int2* __restrict__ edges,
                                                const float* __restrict__ invdeg,
                                                const float* __restrict__ bias,
                                                const float* __restrict__ W2,
                                                __hip_bfloat16* __restrict__ Ybf2) {
    __shared__ float Ws[64 * 64];
    __shared__ float rowbuf[4][4][64];   // [wave][r][j]
    for (int i = threadIdx.x; i < 64 * 64; i += 256) Ws[i] = W2[i];
    __syncthreads();
    int wave = threadIdx.x >> 6;
    int j    = threadIdx.x & 63;
    int n0   = (blockIdx.x * 4 + wave) * 4;   // N_NODES = 16*3125: exact
    int e0 = off[n0], b1v = off[n0 + 1], b2v = off[n0 + 2], b3v = off[n0 + 3], e4 = off[n0 + 4];
    float a0 = __bfloat162float(Hbf[(size_t)(n0 + 0) * DIM + j]) * invdeg[n0 + 0];
    float a1 = __bfloat162float(Hbf[(size_t)(n0 + 1) * DIM + j]) * invdeg[n0 + 1];
    float a2 = __bfloat162float(Hbf[(size_t)(n0 + 2) * DIM + j]) * invdeg[n0 + 2];
    float a3 = __bfloat162float(Hbf[(size_t)(n0 + 3) * DIM + j]) * invdeg[n0 + 3];
    gather_stream4(Hbf, edges, e0, b1v, b2v, b3v, e4, j, a0, a1, a2, a3);
    float bj = bias[j];
    rowbuf[wave][0][j] = fmaxf(a0 + bj, 0.f);
    rowbuf[wave][1][j] = fmaxf(a1 + bj, 0.f);
    rowbuf[wave][2][j] = fmaxf(a2 + bj, 0.f);
    rowbuf[wave][3][j] = fmaxf(a3 + bj, 0.f);
    // same-wave LDS write->read: compiler inserts lgkmcnt wait; no barrier needed
    float acc2[4] = {0.f, 0.f, 0.f, 0.f};
#pragma unroll
    for (int k4 = 0; k4 < 16; ++k4) {
        float w0 = Ws[(4 * k4 + 0) * 64 + j];
        float w1 = Ws[(4 * k4 + 1) * 64 + j];
        float w2 = Ws[(4 * k4 + 2) * 64 + j];
        float w3 = Ws[(4 * k4 + 3) * 64 + j];
#pragma unroll
        for (int r = 0; r < 4; ++r) {
            float4 h4 = *(const float4*)&rowbuf[wave][r][k4 * 4];  // broadcast: free
            acc2[r] = fmaf(h4.x, w0, acc2[r]);
            acc2[r] = fmaf(h4.y, w1, acc2[r]);
            acc2[r] = fmaf(h4.z, w2, acc2[r]);
            acc2[r] = fmaf(h4.w, w3, acc2[r]);
        }
    }
#pragma unroll
    for (int r = 0; r < 4; ++r)
        Ybf2[(size_t)(n0 + r) * DIM + j] = __float2bfloat16(acc2[r]);
}

// ---- layer-2 aggregate (+bias2, relu) fused with mean-pool accumulation ----
// Wave's 4 nodes usually share one graph (sorted batch, ~98 nodes/graph):
// pre-reduce 4 rows -> 1 atomicAdd per lane into sums[g*64+j].

__global__ __launch_bounds__(256) void agg_pool(const __hip_bfloat16* __restrict__ Hbf,
                                                const int* __restrict__ off,
                                                const int2* __restrict__ edges,
                                                const float* __restrict__ invdeg,
                                                const float* __restrict__ bias,
                                                const int* __restrict__ batch,
                                                float* __restrict__ sums) {
    int wave = threadIdx.x >> 6;
    int j    = threadIdx.x & 63;
    int n0   = (blockIdx.x * 4 + wave) * 4;   // exact
    int e0 = off[n0], b1v = off[n0 + 1], b2v = off[n0 + 2], b3v = off[n0 + 3], e4 = off[n0 + 4];
    float a0 = __bfloat162float(Hbf[(size_t)(n0 + 0) * DIM + j]) * invdeg[n0 + 0];
    float a1 = __bfloat162float(Hbf[(size_t)(n0 + 1) * DIM + j]) * invdeg[n0 + 1];
    float a2 = __bfloat162float(Hbf[(size_t)(n0 + 2) * DIM + j]) * invdeg[n0 + 2];
    float a3 = __bfloat162float(Hbf[(size_t)(n0 + 3) * DIM + j]) * invdeg[n0 + 3];
    gather_stream4(Hbf, edges, e0, b1v, b2v, b3v, e4, j, a0, a1, a2, a3);
    float bj = bias[j];
    float r0 = fmaxf(a0 + bj, 0.f);
    float r1 = fmaxf(a1 + bj, 0.f);
    float r2 = fmaxf(a2 + bj, 0.f);
    float r3 = fmaxf(a3 + bj, 0.f);
    int g0 = batch[n0], g3 = batch[n0 + 3];
    if (g0 == g3) {
        atomicAdd(&sums[g0 * DIM + j], ((r0 + r1) + (r2 + r3)));
    } else {
        int g1 = batch[n0 + 1], g2 = batch[n0 + 2];
        atomicAdd(&sums[g0 * DIM + j], r0);
        atomicAdd(&sums[g1 * DIM + j], r1);
        atomicAdd(&sums[g2 * DIM + j], r2);
        atomicAdd(&sums[g3 * DIM + j], r3);
    }
}

// ---- FC over pooled means: one 64-thread block per graph ----

__global__ __launch_bounds__(64) void fc(const float* __restrict__ sums,
                                         const int* __restrict__ batch,
                                         const float* __restrict__ fcW,
                                         const float* __restrict__ fcb,
                                         float* __restrict__ out) {
    __shared__ float mean[64];
    int g = blockIdx.x;
    int lo = 0, hi = N_NODES;
    while (lo < hi) { int mid = (lo + hi) >> 1; if (batch[mid] < g) lo = mid + 1; else hi = mid; }
    int start = lo;
    hi = N_NODES;
    while (lo < hi) { int mid = (lo + hi) >> 1; if (batch[mid] < g + 1) lo = mid + 1; else hi = mid; }
    int end = lo;
    float inv = 1.0f / fmaxf((float)(end - start), 1.0f);
    mean[threadIdx.x] = sums[g * DIM + threadIdx.x] * inv;   // same-wave LDS, no barrier
    if (threadIdx.x < ODIM) {
        int jj = threadIdx.x;
        float a = fcb[jj];
#pragma unroll
        for (int k = 0; k < DIM; ++k) a = fmaf(mean[k], fcW[k * ODIM + jj], a);
        out[g * ODIM + jj] = a;
    }
}

extern "C" void kernel_launch(void* const* d_in, const int* in_sizes, int n_in,
                              void* d_out, int out_size, void* d_ws, size_t ws_size,
                              hipStream_t stream) {
    const float* x    = (const float*)d_in[0];
    const float* W1   = (const float*)d_in[1];
    const float* b1   = (const float*)d_in[2];
    const float* W2   = (const float*)d_in[3];
    const float* b2   = (const float*)d_in[4];
    const float* fcW  = (const float*)d_in[5];
    const float* fcb  = (const float*)d_in[6];
    const int*   eidx = (const int*)d_in[7];
    const int*   batch= (const int*)d_in[8];
    const int* esrc = eidx;
    const int* edst = eidx + N_EDGES;
    float* out = (float*)d_out;

    char* ws = (char*)d_ws;
    size_t o = 0;
    auto alloc = [&](size_t bytes) {
        void* p = ws + o;
        o += (bytes + 255) & ~(size_t)255;
        return p;
    };
    __hip_bfloat16* bf1 = (__hip_bfloat16*)alloc((size_t)N_NODES * DIM * 2);
    __hip_bfloat16* bf2 = (__hip_bfloat16*)alloc((size_t)N_NODES * DIM * 2);
    int*   cnt      = (int*)  alloc((size_t)N_NODES * 4);
    int*   off      = (int*)  alloc((size_t)(N_NODES + 1) * 4);
    int*   cursor   = (int*)  alloc((size_t)N_NODES * 4);
    float* inv_sqrt = (float*)alloc((size_t)N_NODES * 4);
    float* invdeg   = (float*)alloc((size_t)N_NODES * 4);
    int2*  edges    = (int2*) alloc((size_t)N_EDGES * 8);
    int*   blocksum = (int*)  alloc((size_t)SCAN_NB * 4);
    float* sums     = (float*)alloc((size_t)N_GRAPHS * DIM * 4);

    hipMemsetAsync(cnt,  0, (size_t)N_NODES * 4, stream);
    hipMemsetAsync(sums, 0, (size_t)N_GRAPHS * DIM * 4, stream);

    count_deg<<<(N_EDGES + 255) / 256, 256, 0, stream>>>(edst, cnt);
    scan_p1<<<SCAN_NB, 256, 0, stream>>>(cnt, blocksum);
    scan_p3<<<SCAN_NB, 256, 0, stream>>>(cnt, blocksum, off, cursor, inv_sqrt, invdeg);
    scatter_edges<<<((N_EDGES + 255) / 256) * NXCD, 256, 0, stream>>>(esrc, edst, inv_sqrt, cursor, edges);

    gemm64<<<(N_NODES + 31) / 32, 256, 0, stream>>>(x, W1, bf1, N_NODES);
    agg_gemm<<<N_NODES / 16, 256, 0, stream>>>(bf1, off, edges, invdeg, b1, W2, bf2);
    agg_pool<<<N_NODES / 16, 256, 0, stream>>>(bf2, off, edges, invdeg, b2, batch, sums);

    fc<<<N_GRAPHS, 64, 0, stream>>>(sums, batch, fcW, fcb, out);
}

// Round 16
// 259.057 us; speedup vs baseline: 1.1810x; 1.1152x over previous
//
#include <hip/hip_runtime.h>
#include <hip/hip_bf16.h>

#define N_NODES 50000
#define N_EDGES 800000
#define DIM 64
#define ODIM 32
#define N_GRAPHS 512
#define SCAN_NB ((N_NODES + 255) / 256)   // 196
#define NXCD 8
#define DST_RANGE ((N_NODES + NXCD - 1) / NXCD)   // 6250

// ---- graph prep: counting-sort edges by dst into CSR ----

__global__ void count_deg(const int* __restrict__ dst, int* __restrict__ cnt) {
    int e = blockIdx.x * blockDim.x + threadIdx.x;
    if (e < N_EDGES) atomicAdd(&cnt[__builtin_nontemporal_load(&dst[e])], 1);
}

// ---- 2-phase exclusive scan over cnt[N_NODES] ----

__global__ __launch_bounds__(256) void scan_p1(const int* __restrict__ cnt,
                                               int* __restrict__ blocksum) {
    __shared__ int ws[4];
    int i = blockIdx.x * 256 + threadIdx.x;
    int v = (i < N_NODES) ? cnt[i] : 0;
    for (int d = 32; d > 0; d >>= 1) v += __shfl_down(v, d, 64);
    int lane = threadIdx.x & 63, wid = threadIdx.x >> 6;
    if (lane == 0) ws[wid] = v;
    __syncthreads();
    if (threadIdx.x == 0) blocksum[blockIdx.x] = ws[0] + ws[1] + ws[2] + ws[3];
}

__global__ __launch_bounds__(256) void scan_p3(const int* __restrict__ cnt,
                                               const int* __restrict__ blocksum,
                                               int* __restrict__ off,
                                               int* __restrict__ cursor,
                                               float* __restrict__ inv_sqrt,
                                               float* __restrict__ invdeg) {
    __shared__ int wtot[4];
    __shared__ int bb[SCAN_NB + 1];
    {
        int t = threadIdx.x;
        int v = (t < SCAN_NB) ? blocksum[t] : 0;
        int lane = t & 63, wid = t >> 6;
        int incl = v;
        for (int d = 1; d < 64; d <<= 1) {
            int u = __shfl_up(incl, d, 64);
            if (lane >= d) incl += u;
        }
        if (lane == 63) wtot[wid] = incl;
        __syncthreads();
        int base = 0;
        for (int w = 0; w < wid; ++w) base += wtot[w];
        incl += base;
        if (t <= SCAN_NB) bb[t] = incl - v;   // exclusive; bb[SCAN_NB] = total
        __syncthreads();
    }
    if (blockIdx.x == 0 && threadIdx.x == 0) off[N_NODES] = bb[SCAN_NB];
    __syncthreads();

    int i = blockIdx.x * 256 + threadIdx.x;
    int v = (i < N_NODES) ? cnt[i] : 0;
    int lane = threadIdx.x & 63, wid = threadIdx.x >> 6;
    int incl = v;
    for (int d = 1; d < 64; d <<= 1) {
        int u = __shfl_up(incl, d, 64);
        if (lane >= d) incl += u;
    }
    __syncthreads();
    if (lane == 63) wtot[wid] = incl;
    __syncthreads();
    int base = bb[blockIdx.x];
    for (int w = 0; w < wid; ++w) base += wtot[w];
    int excl = base + incl - v;
    if (i < N_NODES) {
        off[i] = excl; cursor[i] = excl;
        float d = (float)(v + 1);   // self-loop
        inv_sqrt[i] = rsqrtf(d);
        invdeg[i]   = 1.0f / d;
    }
}

// XCD-partitioned scatter: block = (chunk, range); blockIdx%8 -> XCD round-robin
__global__ void scatter_edges(const int* __restrict__ src, const int* __restrict__ dst,
                              const float* __restrict__ inv_sqrt,
                              int* __restrict__ cursor,
                              int2* __restrict__ edges) {
    int chunk = blockIdx.x >> 3;
    int range = blockIdx.x & 7;
    int e = chunk * 256 + threadIdx.x;
    if (e >= N_EDGES) return;
    int d = dst[e];
    int lo = range * DST_RANGE;
    if ((unsigned)(d - lo) < (unsigned)DST_RANGE) {
        int s = src[e];
        int pos = atomicAdd(&cursor[d], 1);
        float w = inv_sqrt[s] * inv_sqrt[d];
        edges[pos] = make_int2(s, __float_as_int(w));
    }
}

// ---- packed merged-stream gather for 4 consecutive nodes ----
// H viewed as uint rows of 32 (2 bf16 features per uint). Lane = (m, h):
// half-wave h handles edges k+2i+h; one gather instruction serves 2 edges
// (2 rows x 128B). Halves are combined by the caller via shfl_xor(32).
__device__ __forceinline__ void gather4_packed(
    const unsigned int* __restrict__ H2,
    const int2* __restrict__ edges,
    int e0, int b1, int b2, int b3, int e4, int m, int h,
    float (&aLo)[4], float (&aHi)[4])
{
    int k = e0;
    int B = (e4 - e0) >> 3;

    int2 Ec[4]; unsigned int Uc[4];
    int2 En[4];

    auto ld4 = [&](int2* E, int kb) {
#pragma unroll
        for (int i = 0; i < 4; ++i) E[i] = edges[kb + 2 * i + h];
    };
    auto gt4 = [&](unsigned int* U, const int2* E) {
#pragma unroll
        for (int i = 0; i < 4; ++i)
            U[i] = H2[(size_t)E[i].x * 32 + m];
    };
    auto consume = [&](const int2* E, const unsigned int* U, int kb) {
        int selA = (kb >= b1) + (kb >= b2) + (kb >= b3);
        int selB = (kb + 7 >= b1) + (kb + 7 >= b2) + (kb + 7 >= b3);
        if (selA == selB) {                 // whole batch in one node (common)
            float sLo = 0.f, sHi = 0.f;
#pragma unroll
            for (int i = 0; i < 4; ++i) {
                float w = __int_as_float(E[i].y);
                sLo = fmaf(__uint_as_float(U[i] << 16), w, sLo);
                sHi = fmaf(__uint_as_float(U[i] & 0xffff0000u), w, sHi);
            }
            if      (selA == 0) { aLo[0] += sLo; aHi[0] += sHi; }
            else if (selA == 1) { aLo[1] += sLo; aHi[1] += sHi; }
            else if (selA == 2) { aLo[2] += sLo; aHi[2] += sHi; }
            else                { aLo[3] += sLo; aHi[3] += sHi; }
        } else {                            // boundary batch: per-edge select
#pragma unroll
            for (int i = 0; i < 4; ++i) {
                int kk = kb + 2 * i + h;
                float w = __int_as_float(E[i].y);
                float pLo = __uint_as_float(U[i] << 16) * w;
                float pHi = __uint_as_float(U[i] & 0xffff0000u) * w;
                int sel = (kk >= b1) + (kk >= b2) + (kk >= b3);
                aLo[0] += (sel == 0) ? pLo : 0.f;  aHi[0] += (sel == 0) ? pHi : 0.f;
                aLo[1] += (sel == 1) ? pLo : 0.f;  aHi[1] += (sel == 1) ? pHi : 0.f;
                aLo[2] += (sel == 2) ? pLo : 0.f;  aHi[2] += (sel == 2) ? pHi : 0.f;
                aLo[3] += (sel == 3) ? pLo : 0.f;  aHi[3] += (sel == 3) ? pHi : 0.f;
            }
        }
    };

    if (B >= 2) {
        ld4(Ec, k);
        gt4(Uc, Ec);
        ld4(En, k + 8);
        for (int b = 0; b < B - 2; ++b) {
            unsigned int Un[4];
            gt4(Un, En);          // gathers batch b+1 in flight
            int2 Ef[4];
            ld4(Ef, k + 16);      // edge loads batch b+2 in flight
            consume(Ec, Uc, k);   // waits only on batch b gathers
#pragma unroll
            for (int i = 0; i < 4; ++i) { Ec[i] = En[i]; Uc[i] = Un[i]; En[i] = Ef[i]; }
            k += 8;
        }
        {
            unsigned int Un[4];
            gt4(Un, En);
            consume(Ec, Uc, k);
#pragma unroll
            for (int i = 0; i < 4; ++i) { Ec[i] = En[i]; Uc[i] = Un[i]; }
            k += 8;
            consume(Ec, Uc, k);
            k += 8;
        }
    } else if (B == 1) {
        ld4(Ec, k); gt4(Uc, Ec); consume(Ec, Uc, k); k += 8;
    }
    for (; k < e4; ++k) {
        if ((k & 1) == h) {       // split tail edges between halves
            int2 e = edges[k];
            unsigned int u = H2[(size_t)e.x * 32 + m];
            float w = __int_as_float(e.y);
            float pLo = __uint_as_float(u << 16) * w;
            float pHi = __uint_as_float(u & 0xffff0000u) * w;
            int sel = (k >= b1) + (k >= b2) + (k >= b3);
            aLo[0] += (sel == 0) ? pLo : 0.f;  aHi[0] += (sel == 0) ? pHi : 0.f;
            aLo[1] += (sel == 1) ? pLo : 0.f;  aHi[1] += (sel == 1) ? pHi : 0.f;
            aLo[2] += (sel == 2) ? pLo : 0.f;  aHi[2] += (sel == 2) ? pHi : 0.f;
            aLo[3] += (sel == 3) ? pLo : 0.f;  aHi[3] += (sel == 3) ? pHi : 0.f;
        }
    }
}

// ---- h = X @ W  (N x 64 @ 64 x 64); bf16 output only ----
// W in NATURAL [k][j] layout in LDS (2-way alias only: free).

__global__ __launch_bounds__(256) void gemm64(const float* __restrict__ X,
                                              const float* __restrict__ W,
                                              __hip_bfloat16* __restrict__ Ybf,
                                              int nrows) {
    __shared__ float Ws[64 * 64];
    for (int i = threadIdx.x; i < 64 * 64; i += 256) Ws[i] = W[i];
    __syncthreads();
    int wave = threadIdx.x >> 6;
    int j    = threadIdx.x & 63;
    int row0 = (blockIdx.x * 4 + wave) * 8;
    if (row0 >= nrows) return;
    float acc[8] = {0,0,0,0,0,0,0,0};
    const float* x0 = X + (size_t)row0 * DIM;   // wave-uniform
    int nr = (row0 + 8 <= nrows) ? 8 : (nrows - row0);
    if (nr == 8) {
#pragma unroll
        for (int k4 = 0; k4 < 16; ++k4) {
            float w0 = Ws[(4 * k4 + 0) * 64 + j];
            float w1 = Ws[(4 * k4 + 1) * 64 + j];
            float w2 = Ws[(4 * k4 + 2) * 64 + j];
            float w3 = Ws[(4 * k4 + 3) * 64 + j];
#pragma unroll
            for (int r = 0; r < 8; ++r) {
                float4 x4 = *(const float4*)&x0[r * DIM + k4 * 4];
                acc[r] = fmaf(x4.x, w0, acc[r]);
                acc[r] = fmaf(x4.y, w1, acc[r]);
                acc[r] = fmaf(x4.z, w2, acc[r]);
                acc[r] = fmaf(x4.w, w3, acc[r]);
            }
        }
    } else {
        for (int k4 = 0; k4 < 16; ++k4) {
            float w0 = Ws[(4 * k4 + 0) * 64 + j];
            float w1 = Ws[(4 * k4 + 1) * 64 + j];
            float w2 = Ws[(4 * k4 + 2) * 64 + j];
            float w3 = Ws[(4 * k4 + 3) * 64 + j];
            for (int r = 0; r < nr; ++r) {
                float4 x4 = *(const float4*)&x0[r * DIM + k4 * 4];
                acc[r] = fmaf(x4.x, w0, acc[r]);
                acc[r] = fmaf(x4.y, w1, acc[r]);
                acc[r] = fmaf(x4.z, w2, acc[r]);
                acc[r] = fmaf(x4.w, w3, acc[r]);
            }
        }
    }
    for (int r = 0; r < nr; ++r)
        Ybf[(size_t)(row0 + r) * DIM + j] = __float2bfloat16(acc[r]);
}

// ---- fused: layer-1 aggregate (+bias1, relu) THEN layer-2 gemm (@W2) ----
// Packed gather; halves combined via shfl_xor; rowbuf written by half 0.

__global__ __launch_bounds__(256) void agg_gemm(const __hip_bfloat16* __restrict__ Hbf,
                                                const int* __restrict__ off,
                                                const int2* __restrict__ edges,
                                                const float* __restrict__ invdeg,
                                                const float* __restrict__ bias,
                                                const float* __restrict__ W2,
                                                __hip_bfloat16* __restrict__ Ybf2) {
    __shared__ float Ws[64 * 64];
    __shared__ float rowbuf[4][4][64];   // [wave][r][j]
    for (int i = threadIdx.x; i < 64 * 64; i += 256) Ws[i] = W2[i];
    __syncthreads();
    const unsigned int* H2 = (const unsigned int*)Hbf;
    int wave = threadIdx.x >> 6;
    int j    = threadIdx.x & 63;
    int m = j & 31, h = j >> 5;
    int n0   = (blockIdx.x * 4 + wave) * 4;   // N_NODES = 16*3125: exact
    int e0 = off[n0], b1v = off[n0 + 1], b2v = off[n0 + 2], b3v = off[n0 + 3], e4 = off[n0 + 4];
    float aLo[4] = {0.f, 0.f, 0.f, 0.f};
    float aHi[4] = {0.f, 0.f, 0.f, 0.f};
    gather4_packed(H2, edges, e0, b1v, b2v, b3v, e4, m, h, aLo, aHi);
    float bLo = bias[2 * m], bHi = bias[2 * m + 1];
#pragma unroll
    for (int r = 0; r < 4; ++r) {
        aLo[r] += __shfl_xor(aLo[r], 32);
        aHi[r] += __shfl_xor(aHi[r], 32);
        unsigned int u = H2[(size_t)(n0 + r) * 32 + m];   // self row
        float iv = invdeg[n0 + r];
        float vLo = fmaf(__uint_as_float(u << 16),          iv, aLo[r]) + bLo;
        float vHi = fmaf(__uint_as_float(u & 0xffff0000u), iv, aHi[r]) + bHi;
        if (h == 0) {
            rowbuf[wave][r][2 * m]     = fmaxf(vLo, 0.f);
            rowbuf[wave][r][2 * m + 1] = fmaxf(vHi, 0.f);
        }
    }
    // same-wave LDS write->read: compiler inserts lgkmcnt wait; no barrier needed
    float acc2[4] = {0.f, 0.f, 0.f, 0.f};
#pragma unroll
    for (int k4 = 0; k4 < 16; ++k4) {
        float w0 = Ws[(4 * k4 + 0) * 64 + j];
        float w1 = Ws[(4 * k4 + 1) * 64 + j];
        float w2 = Ws[(4 * k4 + 2) * 64 + j];
        float w3 = Ws[(4 * k4 + 3) * 64 + j];
#pragma unroll
        for (int r = 0; r < 4; ++r) {
            float4 h4 = *(const float4*)&rowbuf[wave][r][k4 * 4];  // broadcast: free
            acc2[r] = fmaf(h4.x, w0, acc2[r]);
            acc2[r] = fmaf(h4.y, w1, acc2[r]);
            acc2[r] = fmaf(h4.z, w2, acc2[r]);
            acc2[r] = fmaf(h4.w, w3, acc2[r]);
        }
    }
#pragma unroll
    for (int r = 0; r < 4; ++r)
        Ybf2[(size_t)(n0 + r) * DIM + j] = __float2bfloat16(acc2[r]);
}

// ---- layer-2 aggregate (+bias2, relu) fused with mean-pool accumulation ----
// Packed gather; atomics from half 0 only (2 per lane).

__global__ __launch_bounds__(256) void agg_pool(const __hip_bfloat16* __restrict__ Hbf,
                                                const int* __restrict__ off,
                                                const int2* __restrict__ edges,
                                                const float* __restrict__ invdeg,
                                                const float* __restrict__ bias,
                                                const int* __restrict__ batch,
                                                float* __restrict__ sums) {
    const unsigned int* H2 = (const unsigned int*)Hbf;
    int wave = threadIdx.x >> 6;
    int j    = threadIdx.x & 63;
    int m = j & 31, h = j >> 5;
    int n0   = (blockIdx.x * 4 + wave) * 4;   // exact
    int e0 = off[n0], b1v = off[n0 + 1], b2v = off[n0 + 2], b3v = off[n0 + 3], e4 = off[n0 + 4];
    float aLo[4] = {0.f, 0.f, 0.f, 0.f};
    float aHi[4] = {0.f, 0.f, 0.f, 0.f};
    gather4_packed(H2, edges, e0, b1v, b2v, b3v, e4, m, h, aLo, aHi);
    float bLo = bias[2 * m], bHi = bias[2 * m + 1];
    float vLo[4], vHi[4];
#pragma unroll
    for (int r = 0; r < 4; ++r) {
        aLo[r] += __shfl_xor(aLo[r], 32);
        aHi[r] += __shfl_xor(aHi[r], 32);
        unsigned int u = H2[(size_t)(n0 + r) * 32 + m];
        float iv = invdeg[n0 + r];
        vLo[r] = fmaxf(fmaf(__uint_as_float(u << 16),          iv, aLo[r]) + bLo, 0.f);
        vHi[r] = fmaxf(fmaf(__uint_as_float(u & 0xffff0000u), iv, aHi[r]) + bHi, 0.f);
    }
    if (h == 0) {
        int g0 = batch[n0], g3 = batch[n0 + 3];
        if (g0 == g3) {
            atomicAdd(&sums[g0 * DIM + 2 * m],     (vLo[0] + vLo[1]) + (vLo[2] + vLo[3]));
            atomicAdd(&sums[g0 * DIM + 2 * m + 1], (vHi[0] + vHi[1]) + (vHi[2] + vHi[3]));
        } else {
#pragma unroll
            for (int r = 0; r < 4; ++r) {
                int g = batch[n0 + r];
                atomicAdd(&sums[g * DIM + 2 * m],     vLo[r]);
                atomicAdd(&sums[g * DIM + 2 * m + 1], vHi[r]);
            }
        }
    }
}

// ---- FC over pooled means: one 64-thread block per graph ----

__global__ __launch_bounds__(64) void fc(const float* __restrict__ sums,
                                         const int* __restrict__ batch,
                                         const float* __restrict__ fcW,
                                         const float* __restrict__ fcb,
                                         float* __restrict__ out) {
    __shared__ float mean[64];
    int g = blockIdx.x;
    int lo = 0, hi = N_NODES;
    while (lo < hi) { int mid = (lo + hi) >> 1; if (batch[mid] < g) lo = mid + 1; else hi = mid; }
    int start = lo;
    hi = N_NODES;
    while (lo < hi) { int mid = (lo + hi) >> 1; if (batch[mid] < g + 1) lo = mid + 1; else hi = mid; }
    int end = lo;
    float inv = 1.0f / fmaxf((float)(end - start), 1.0f);
    mean[threadIdx.x] = sums[g * DIM + threadIdx.x] * inv;   // same-wave LDS, no barrier
    if (threadIdx.x < ODIM) {
        int jj = threadIdx.x;
        float a = fcb[jj];
#pragma unroll
        for (int k = 0; k < DIM; ++k) a = fmaf(mean[k], fcW[k * ODIM + jj], a);
        out[g * ODIM + jj] = a;
    }
}

extern "C" void kernel_launch(void* const* d_in, const int* in_sizes, int n_in,
                              void* d_out, int out_size, void* d_ws, size_t ws_size,
                              hipStream_t stream) {
    const float* x    = (const float*)d_in[0];
    const float* W1   = (const float*)d_in[1];
    const float* b1   = (const float*)d_in[2];
    const float* W2   = (const float*)d_in[3];
    const float* b2   = (const float*)d_in[4];
    const float* fcW  = (const float*)d_in[5];
    const float* fcb  = (const float*)d_in[6];
    const int*   eidx = (const int*)d_in[7];
    const int*   batch= (const int*)d_in[8];
    const int* esrc = eidx;
    const int* edst = eidx + N_EDGES;
    float* out = (float*)d_out;

    char* ws = (char*)d_ws;
    size_t o = 0;
    auto alloc = [&](size_t bytes) {
        void* p = ws + o;
        o += (bytes + 255) & ~(size_t)255;
        return p;
    };
    __hip_bfloat16* bf1 = (__hip_bfloat16*)alloc((size_t)N_NODES * DIM * 2);
    __hip_bfloat16* bf2 = (__hip_bfloat16*)alloc((size_t)N_NODES * DIM * 2);
    int*   cnt      = (int*)  alloc((size_t)N_NODES * 4);
    int*   off      = (int*)  alloc((size_t)(N_NODES + 1) * 4);
    int*   cursor   = (int*)  alloc((size_t)N_NODES * 4);
    float* inv_sqrt = (float*)alloc((size_t)N_NODES * 4);
    float* invdeg   = (float*)alloc((size_t)N_NODES * 4);
    int2*  edges    = (int2*) alloc((size_t)N_EDGES * 8);
    int*   blocksum = (int*)  alloc((size_t)SCAN_NB * 4);
    float* sums     = (float*)alloc((size_t)N_GRAPHS * DIM * 4);

    hipMemsetAsync(cnt,  0, (size_t)N_NODES * 4, stream);
    hipMemsetAsync(sums, 0, (size_t)N_GRAPHS * DIM * 4, stream);

    count_deg<<<(N_EDGES + 255) / 256, 256, 0, stream>>>(edst, cnt);
    scan_p1<<<SCAN_NB, 256, 0, stream>>>(cnt, blocksum);
    scan_p3<<<SCAN_NB, 256, 0, stream>>>(cnt, blocksum, off, cursor, inv_sqrt, invdeg);
    scatter_edges<<<((N_EDGES + 255) / 256) * NXCD, 256, 0, stream>>>(esrc, edst, inv_sqrt, cursor, edges);

    gemm64<<<(N_NODES + 31) / 32, 256, 0, stream>>>(x, W1, bf1, N_NODES);
    agg_gemm<<<N_NODES / 16, 256, 0, stream>>>(bf1, off, edges, invdeg, b1, W2, bf2);
    agg_pool<<<N_NODES / 16, 256, 0, stream>>>(bf2, off, edges, invdeg, b2, batch, sums);

    fc<<<N_GRAPHS, 64, 0, stream>>>(sums, batch, fcW, fcb, out);
}